// Round 8
// baseline (946.251 us; speedup 1.0000x reference)
//
#include <hip/hip_runtime.h>
#include <hip/hip_fp16.h>

#define NG 50000
#define NC 100000
#define DIN 128
#define D 64
#define EGG 800000
#define ECG 1600000
#define ECC 1600000
#define LN_EPS 1e-5f

#define SCAN_N (2 * NG + NC)            // 200000 concatenated counters
#define SCAN_TPB 256
#define SCAN_PER_THREAD 8
#define SCAN_TILE (SCAN_TPB * SCAN_PER_THREAD)   // 2048
#define SCAN_NBLK ((SCAN_N + SCAN_TILE - 1) / SCAN_TILE)  // 98

__device__ __forceinline__ float wave_sum64(float v) {
#pragma unroll
  for (int off = 32; off > 0; off >>= 1) v += __shfl_xor(v, off);
  return v;
}

// ---- pipelined fp16 CSR gather -------------------------------------------
// Pair-edge layout: lane = h*32+m (h = edge parity, m = dim pair). One half2
// load covers 2 dims of 1 of 2 edges; a 16-edge group = 8 loads/lane.
// Depth-2 pipeline: group j+16 is issued before group j is consumed ->
// 16 outstanding loads/wave in steady state. First-chunk indices/weights can
// be preloaded by the caller (pidx/pw) so the index miss overlaps earlier work.

__device__ __forceinline__ void gather_issue(
    const __half* __restrict__ tab, int sidx, int h, int m, int j,
    __half2* g) {
#pragma unroll
  for (int p = 0; p < 8; ++p) {
    int s = __shfl(sidx, j + 2 * p + h);
    g[p] = *(const __half2*)(tab + (size_t)s * D + 2 * m);
  }
}

__device__ __forceinline__ void gather_consume(
    float w, int h, int j, const __half2* g, float* ax, float* ay) {
#pragma unroll
  for (int p = 0; p < 8; ++p) {
    float wp = __shfl(w, j + 2 * p + h);
    ax[p] = fmaf(wp, __low2float(g[p]), ax[p]);
    ay[p] = fmaf(wp, __high2float(g[p]), ay[p]);
  }
}

// Returns sum_e w_e * tab[src_e*64 + lane] (lane = dim layout).
// pidx/pw: preloaded index/weight for element e0+lane (w=0 for masked lanes).
__device__ __forceinline__ float csr_gather_h2(
    const int* __restrict__ src, const float* __restrict__ nrm,
    const __half* __restrict__ tab, int e0, int e1, int lane,
    int pidx, float pw) {
  int h = lane >> 5;
  int m = lane & 31;
  float ax[8], ay[8];
#pragma unroll
  for (int p = 0; p < 8; ++p) { ax[p] = 0.0f; ay[p] = 0.0f; }
  bool first = true;
  for (int base = e0; base < e1; base += 64) {
    int cnt = e1 - base; if (cnt > 64) cnt = 64;
    int sidx; float w;
    if (first) {
      sidx = pidx; w = pw;
    } else {
      sidx = 0; w = 0.0f;
      if (lane < cnt) {
        sidx = src[base + lane];
        w = nrm ? nrm[base + lane] : 1.0f;
      }
    }
    first = false;
    int jend = (cnt + 15) & ~15;
    __half2 v[8], u[8];
    gather_issue(tab, sidx, h, m, 0, v);
    int j = 0;
    while (true) {
      if (j + 16 < jend) gather_issue(tab, sidx, h, m, j + 16, u);
      gather_consume(w, h, j, v, ax, ay);
      j += 16;
      if (j >= jend) break;
      if (j + 16 < jend) gather_issue(tab, sidx, h, m, j + 16, v);
      gather_consume(w, h, j, u, ax, ay);
      j += 16;
      if (j >= jend) break;
    }
  }
  float sx = ((ax[0] + ax[1]) + (ax[2] + ax[3])) + ((ax[4] + ax[5]) + (ax[6] + ax[7]));
  float sy = ((ay[0] + ay[1]) + (ay[2] + ay[3])) + ((ay[4] + ay[5]) + (ay[6] + ay[7]));
  sx += __shfl_xor(sx, 32);   // combine even/odd edge halves
  sy += __shfl_xor(sy, 32);
  // redistribute pair layout -> lane=dim: lane d takes comp (d&1) of pair d>>1
  float ev = __shfl(sx, lane >> 1);
  float od = __shfl(sy, lane >> 1);
  return (lane & 1) ? od : ev;
}

// ---------------- dense input FC: y = relu(LN(x @ W + b)) -> fp16 ----------
__global__ __launch_bounds__(256) void fc_in_kernel(
    const float* __restrict__ x, const float* __restrict__ W,
    const float* __restrict__ b, const float* __restrict__ s,
    const float* __restrict__ beta, __half* __restrict__ y, int n) {
  int wid = (int)(((size_t)blockIdx.x * blockDim.x + threadIdx.x) >> 6);
  int lane = threadIdx.x & 63;
  if (wid >= n) return;
  const float* xr = x + (size_t)wid * DIN;
  float v0 = xr[lane];
  float v1 = xr[64 + lane];
  float acc = b[lane];
#pragma unroll
  for (int k = 0; k < 64; ++k)
    acc = fmaf(__shfl(v0, k), W[k * 64 + lane], acc);
#pragma unroll
  for (int k = 0; k < 64; ++k)
    acc = fmaf(__shfl(v1, k), W[(k + 64) * 64 + lane], acc);
  float m = wave_sum64(acc) * (1.0f / 64.0f);
  float d = acc - m;
  float var = wave_sum64(d * d) * (1.0f / 64.0f);
  float o = d * rsqrtf(var + LN_EPS) * s[lane] + beta[lane];
  y[(size_t)wid * D + lane] = __float2half(fmaxf(o, 0.0f));
}

// ---------------- CSR build: single atomic pass ----------------------------
__global__ __launch_bounds__(256) void passA_kernel(
    const int* __restrict__ ei_gg, const int* __restrict__ ei_cg,
    const int* __restrict__ ei_cc, int* __restrict__ cnt,
    int* __restrict__ pos_gg, int* __restrict__ pos_cg,
    int* __restrict__ pos_cc) {
  int e = blockIdx.x * 256 + threadIdx.x;
  if (e < EGG) pos_gg[e] = atomicAdd(&cnt[ei_gg[EGG + e]], 1);
  if (e < ECG) pos_cg[e] = atomicAdd(&cnt[NG + ei_cg[ECG + e]], 1);
  if (e < ECC) pos_cc[e] = atomicAdd(&cnt[2 * NG + ei_cc[ECC + e]], 1);
}

// ---------------- hierarchical exclusive scan over cnt[0..SCAN_N) ----------
__global__ __launch_bounds__(SCAN_TPB) void scan_blocksum_kernel(
    const int* __restrict__ cnt, int* __restrict__ bsum) {
  __shared__ int sh[SCAN_TPB / 64];
  int t = threadIdx.x;
  int base = blockIdx.x * SCAN_TILE + t * SCAN_PER_THREAD;
  int s = 0;
#pragma unroll
  for (int k = 0; k < SCAN_PER_THREAD; ++k) {
    int i = base + k;
    if (i < SCAN_N) s += cnt[i];
  }
#pragma unroll
  for (int off = 32; off > 0; off >>= 1) s += __shfl_xor(s, off);
  if ((t & 63) == 0) sh[t >> 6] = s;
  __syncthreads();
  if (t == 0) {
    int tot = 0;
#pragma unroll
    for (int w = 0; w < SCAN_TPB / 64; ++w) tot += sh[w];
    bsum[blockIdx.x] = tot;
  }
}

__global__ void scan_bsum_kernel(int* __restrict__ bsum, int* __restrict__ S) {
  if (threadIdx.x == 0) {
    int acc = 0;
    for (int b = 0; b < SCAN_NBLK; ++b) {
      int v = bsum[b]; bsum[b] = acc; acc += v;
    }
    S[SCAN_N] = acc;
  }
}

__global__ __launch_bounds__(SCAN_TPB) void scan_final_kernel(
    const int* __restrict__ cnt, const int* __restrict__ bsum,
    int* __restrict__ S) {
  int t = threadIdx.x;
  int lane = t & 63;
  int base = blockIdx.x * SCAN_TILE + t * SCAN_PER_THREAD;
  int v[SCAN_PER_THREAD];
  int s = 0;
#pragma unroll
  for (int k = 0; k < SCAN_PER_THREAD; ++k) {
    int i = base + k;
    v[k] = (i < SCAN_N) ? cnt[i] : 0;
    s += v[k];
  }
  int sc = s;
#pragma unroll
  for (int off = 1; off < 64; off <<= 1) {
    int u = __shfl_up(sc, off);
    if (lane >= off) sc += u;
  }
  __shared__ int wsum[SCAN_TPB / 64];
  if (lane == 63) wsum[t >> 6] = sc;
  __syncthreads();
  int wbase = 0;
  for (int w = 0; w < (t >> 6); ++w) wbase += wsum[w];
  int ex = bsum[blockIdx.x] + wbase + (sc - s);
#pragma unroll
  for (int k = 0; k < SCAN_PER_THREAD; ++k) {
    int i = base + k;
    if (i < SCAN_N) S[i] = ex;
    ex += v[k];
  }
}

// ---------------- atomic-free scatter into the unified src buffer ----------
__global__ __launch_bounds__(256) void scatter_kernel(
    const int* __restrict__ ei_gg, const float* __restrict__ ew_gg,
    const int* __restrict__ ei_cg, const int* __restrict__ ei_cc,
    const int* __restrict__ S, const int* __restrict__ pos_gg,
    const int* __restrict__ pos_cg, const int* __restrict__ pos_cc,
    int* __restrict__ srcbuf, float* __restrict__ ewp) {
  int e = blockIdx.x * 256 + threadIdx.x;
  if (e < EGG) {
    int d = ei_gg[EGG + e];
    int p = S[d] + pos_gg[e];
    srcbuf[p] = ei_gg[e];
    ewp[p] = ew_gg[e];
  }
  if (e < ECG) {
    int d = ei_cg[ECG + e];
    int p = S[NG + d] + pos_cg[e];
    srcbuf[p] = ei_cg[e];
  }
  if (e < ECC) {
    int d = ei_cc[ECC + e];
    int p = S[2 * NG + d] + pos_cc[e];
    srcbuf[p] = ei_cc[e];
  }
}

// dinv[i] = rsqrt(1 + segment sum of permuted edge weights)
__global__ __launch_bounds__(256) void deg_kernel(
    const int* __restrict__ S, const float* __restrict__ ewp,
    float* __restrict__ dinv) {
  int i = (int)(((size_t)blockIdx.x * blockDim.x + threadIdx.x) >> 6);
  int lane = threadIdx.x & 63;
  if (i >= NG) return;
  int e0 = S[i], e1 = S[i + 1];
  float s = 0.0f;
  for (int e = e0 + lane; e < e1; e += 64) s += ewp[e];
  s = wave_sum64(s);
  if (lane == 0) dinv[i] = rsqrtf(s + 1.0f);
}

// nrm[e] = dinv[src] * ew * dinv[dst]
__global__ __launch_bounds__(256) void nrm_kernel(
    const int* __restrict__ S, const int* __restrict__ srcbuf,
    const float* __restrict__ ewp, const float* __restrict__ dinv,
    float* __restrict__ nrm) {
  int i = (int)(((size_t)blockIdx.x * blockDim.x + threadIdx.x) >> 6);
  int lane = threadIdx.x & 63;
  if (i >= NG) return;
  float di = dinv[i];
  int e0 = S[i], e1 = S[i + 1];
  for (int e = e0 + lane; e < e1; e += 64)
    nrm[e] = dinv[srcbuf[e]] * ewp[e] * di;
}

// ---------------- fused glom layer -----------------------------------------
__global__ __launch_bounds__(256) void glom_layer_kernel(
    const int* __restrict__ rp_gg, const int* __restrict__ rp_cg,
    const int* __restrict__ srcbuf, const float* __restrict__ nrm_gg,
    const __half* __restrict__ xg_old, const __half* __restrict__ xc_old,
    const float* __restrict__ dinv,
    const float* __restrict__ W_gcn, const float* __restrict__ b_gcn,
    const float* __restrict__ eps_cg, const float* __restrict__ W_cg,
    const float* __restrict__ b_cg,
    const float* __restrict__ ls, const float* __restrict__ lb,
    __half* __restrict__ xg_new, int n) {
  int i = (int)(((size_t)blockIdx.x * blockDim.x + threadIdx.x) >> 6);
  int lane = threadIdx.x & 63;
  if (i >= n) return;
  int ge0 = rp_gg[i], ge1 = rp_gg[i + 1];
  int fe0 = rp_cg[i], fe1 = rp_cg[i + 1];
  // hoist first-chunk index/weight loads for BOTH gathers off the chain
  int gidx = 0; float gw = 0.0f;
  if (ge0 + lane < ge1) { gidx = srcbuf[ge0 + lane]; gw = nrm_gg[ge0 + lane]; }
  int cidx = 0; float cw = 0.0f;
  if (fe0 + lane < fe1) { cidx = srcbuf[fe0 + lane]; cw = 1.0f; }
  float self = __half2float(xg_old[(size_t)i * D + lane]);
  float di = dinv[i];
  float accG = di * di * self
             + csr_gather_h2(srcbuf, nrm_gg, xg_old, ge0, ge1, lane, gidx, gw);
  float accC = csr_gather_h2(srcbuf, nullptr, xc_old, fe0, fe1, lane, cidx, cw);
  float gcn = b_gcn[lane];
#pragma unroll
  for (int k = 0; k < 64; ++k)
    gcn = fmaf(__shfl(accG, k), W_gcn[k * 64 + lane], gcn);
  float h = (1.0f + eps_cg[0]) * self + accC;
  float gin = b_cg[lane];
#pragma unroll
  for (int k = 0; k < 64; ++k)
    gin = fmaf(__shfl(h, k), W_cg[k * 64 + lane], gin);
  float g = gcn + fmaxf(gin, 0.0f);
  float m = wave_sum64(g) * (1.0f / 64.0f);
  float d = g - m;
  float var = wave_sum64(d * d) * (1.0f / 64.0f);
  float o = d * rsqrtf(var + LN_EPS) * ls[lane] + lb[lane];
  xg_new[(size_t)i * D + lane] = __float2half(fmaxf(o, 0.0f));
}

// ---------------- fused cell layer -----------------------------------------
__global__ __launch_bounds__(256) void cell_layer_kernel(
    const int* __restrict__ rp_cc, const int* __restrict__ srcbuf,
    const __half* __restrict__ xc_old,
    const float* __restrict__ eps_cc, const float* __restrict__ W_cc,
    const float* __restrict__ b_cc,
    const float* __restrict__ ls, const float* __restrict__ lb,
    __half* __restrict__ xc_new, int n) {
  int i = (int)(((size_t)blockIdx.x * blockDim.x + threadIdx.x) >> 6);
  int lane = threadIdx.x & 63;
  if (i >= n) return;
  int e0 = rp_cc[i], e1 = rp_cc[i + 1];
  int cidx = 0; float cw = 0.0f;
  if (e0 + lane < e1) { cidx = srcbuf[e0 + lane]; cw = 1.0f; }
  float self = __half2float(xc_old[(size_t)i * D + lane]);
  float acc = csr_gather_h2(srcbuf, nullptr, xc_old, e0, e1, lane, cidx, cw);
  float h = (1.0f + eps_cc[0]) * self + acc;
  float gin = b_cc[lane];
#pragma unroll
  for (int k = 0; k < 64; ++k)
    gin = fmaf(__shfl(h, k), W_cc[k * 64 + lane], gin);
  float g = fmaxf(gin, 0.0f);
  float m = wave_sum64(g) * (1.0f / 64.0f);
  float d = g - m;
  float var = wave_sum64(d * d) * (1.0f / 64.0f);
  float o = d * rsqrtf(var + LN_EPS) * ls[lane] + lb[lane];
  xc_new[(size_t)i * D + lane] = __float2half(fmaxf(o, 0.0f));
}

// ---------------- output head: wave per row --------------------------------
__global__ __launch_bounds__(256) void out_kernel(
    const __half* __restrict__ xg, const float* __restrict__ W,
    const float* __restrict__ b, float* __restrict__ out, int n) {
  int wid = (int)(((size_t)blockIdx.x * blockDim.x + threadIdx.x) >> 6);
  int lane = threadIdx.x & 63;
  if (wid >= n) return;
  float v = __half2float(xg[(size_t)wid * D + lane]);
  float a0 = wave_sum64(v * W[lane * 3 + 0]) + b[0];
  float a1 = wave_sum64(v * W[lane * 3 + 1]) + b[1];
  float a2 = wave_sum64(v * W[lane * 3 + 2]) + b[2];
  float m = fmaxf(a0, fmaxf(a1, a2));
  float e0 = expf(a0 - m), e1 = expf(a1 - m), e2 = expf(a2 - m);
  float inv = 1.0f / (e0 + e1 + e2);
  if (lane == 0) {
    out[(size_t)wid * 3 + 0] = e0 * inv;
    out[(size_t)wid * 3 + 1] = e1 * inv;
    out[(size_t)wid * 3 + 2] = e2 * inv;
  }
}

extern "C" void kernel_launch(void* const* d_in, const int* in_sizes, int n_in,
                              void* d_out, int out_size, void* d_ws, size_t ws_size,
                              hipStream_t stream) {
  const float* x_glom = (const float*)d_in[0];
  const float* x_cell = (const float*)d_in[1];
  const int*   ei_gg  = (const int*)d_in[2];
  const float* ew_gg  = (const float*)d_in[3];
  const int*   ei_cg  = (const int*)d_in[4];
  const int*   ei_cc  = (const int*)d_in[5];
  const float* W_in_g = (const float*)d_in[6];
  const float* b_in_g = (const float*)d_in[7];
  const float* lnig_s = (const float*)d_in[8];
  const float* lnig_b = (const float*)d_in[9];
  const float* W_in_c = (const float*)d_in[10];
  const float* b_in_c = (const float*)d_in[11];
  const float* lnic_s = (const float*)d_in[12];
  const float* lnic_b = (const float*)d_in[13];
  const float* W_outp = (const float*)d_in[34];
  const float* b_outp = (const float*)d_in[35];

  // ---- workspace layout (~60 MB) ----
  char* W0 = (char*)d_ws;
  __half* xg0 = (__half*)W0;                         W0 += (size_t)NG * D * 2;
  __half* xg1 = (__half*)W0;                         W0 += (size_t)NG * D * 2;
  __half* xc0 = (__half*)W0;                         W0 += (size_t)NC * D * 2;
  __half* xc1 = (__half*)W0;                         W0 += (size_t)NC * D * 2;
  float* dinv = (float*)W0;                          W0 += NG * 4;
  float* nrm  = (float*)W0;                          W0 += EGG * 4;
  int* cnt    = (int*)W0;                            W0 += SCAN_N * 4;
  int* S      = (int*)W0;                            W0 += (SCAN_N + 1) * 4;
  int* bsum   = (int*)W0;                            W0 += SCAN_NBLK * 4;
  int* srcbuf = (int*)W0;                            W0 += (size_t)(EGG + ECG + ECC) * 4;
  // transient region (dead before fc_in writes xc0/xc1): pos arrays + permuted ew
  int* pos_gg = (int*)xc0;
  int* pos_cg = pos_gg + EGG;
  int* pos_cc = pos_cg + ECG;
  float* ewp  = (float*)(pos_cc + ECC);

  dim3 blk(256);
  auto wgrid = [](long long waves) { return dim3((unsigned)((waves + 3) / 4)); };
  auto egrid = [](long long e) { return dim3((unsigned)((e + 255) / 256)); };

  // ---- CSR build: 1 atomic pass + hierarchical scan + atomic-free scatter --
  hipMemsetAsync(cnt, 0, SCAN_N * sizeof(int), stream);
  passA_kernel<<<egrid(ECG), blk, 0, stream>>>(
      ei_gg, ei_cg, ei_cc, cnt, pos_gg, pos_cg, pos_cc);
  scan_blocksum_kernel<<<dim3(SCAN_NBLK), dim3(SCAN_TPB), 0, stream>>>(cnt, bsum);
  scan_bsum_kernel<<<dim3(1), dim3(64), 0, stream>>>(bsum, S);
  scan_final_kernel<<<dim3(SCAN_NBLK), dim3(SCAN_TPB), 0, stream>>>(cnt, bsum, S);
  scatter_kernel<<<egrid(ECG), blk, 0, stream>>>(
      ei_gg, ew_gg, ei_cg, ei_cc, S, pos_gg, pos_cg, pos_cc, srcbuf, ewp);
  deg_kernel<<<wgrid(NG), blk, 0, stream>>>(S, ewp, dinv);
  nrm_kernel<<<wgrid(NG), blk, 0, stream>>>(S, srcbuf, ewp, dinv, nrm);

  // ---- input FCs (xc0 write overwrites the transient pos/ewp region) ----
  fc_in_kernel<<<wgrid(NG), blk, 0, stream>>>(x_glom, W_in_g, b_in_g, lnig_s, lnig_b, xg0, NG);
  fc_in_kernel<<<wgrid(NC), blk, 0, stream>>>(x_cell, W_in_c, b_in_c, lnic_s, lnic_b, xc0, NC);

  // ---- two hetero MP layers (double-buffered) ----
  const int* rp_gg = S;
  const int* rp_cg = S + NG;
  const int* rp_cc = S + 2 * NG;
  __half* xg_cur = xg0; __half* xg_nxt = xg1;
  __half* xc_cur = xc0; __half* xc_nxt = xc1;
  for (int l = 0; l < 2; ++l) {
    const float* const* p = (const float* const*)(d_in + 14 + 10 * l);
    const float* W_gcn = p[0]; const float* b_gcn = p[1];
    const float* eps_cg = p[2]; const float* W_cg = p[3]; const float* b_cg = p[4];
    const float* eps_cc = p[5]; const float* W_cc = p[6]; const float* b_cc = p[7];
    const float* ln_s = p[8]; const float* ln_b = p[9];

    glom_layer_kernel<<<wgrid(NG), blk, 0, stream>>>(
        rp_gg, rp_cg, srcbuf, nrm, xg_cur, xc_cur, dinv,
        W_gcn, b_gcn, eps_cg, W_cg, b_cg, ln_s, ln_b, xg_nxt, NG);
    cell_layer_kernel<<<wgrid(NC), blk, 0, stream>>>(
        rp_cc, srcbuf, xc_cur, eps_cc, W_cc, b_cc, ln_s, ln_b, xc_nxt, NC);

    __half* t;
    t = xg_cur; xg_cur = xg_nxt; xg_nxt = t;
    t = xc_cur; xc_cur = xc_nxt; xc_nxt = t;
  }

  out_kernel<<<wgrid(NG), blk, 0, stream>>>(xg_cur, W_outp, b_outp, (float*)d_out, NG);
}

// Round 9
// 817.601 us; speedup vs baseline: 1.1574x; 1.1574x over previous
//
#include <hip/hip_runtime.h>
#include <hip/hip_fp16.h>

#define NG 50000
#define NC 100000
#define DIN 128
#define D 64
#define EGG 800000
#define ECG 1600000
#define ECC 1600000
#define LN_EPS 1e-5f

#define SCAN_N (2 * NG + NC)            // 200000 keys: gg dst | cg dst | cc dst
#define E_ALL (EGG + ECG + ECC)         // 4,000,000 edges
#define NBKT 196                        // buckets of 1024 keys (199999>>10 = 195)
#define NBLK 512                        // blocks in R1/R3
#define EPB ((E_ALL + NBLK - 1) / NBLK) // edges per block = 7813

__device__ __forceinline__ float wave_sum64(float v) {
#pragma unroll
  for (int off = 32; off > 0; off >>= 1) v += __shfl_xor(v, off);
  return v;
}

// ---- pipelined fp16 CSR gather ---------------------------------------------
__device__ __forceinline__ void gather_issue(
    const __half* __restrict__ tab, int sidx, int h, int m, int j,
    __half2* g) {
#pragma unroll
  for (int p = 0; p < 8; ++p) {
    int s = __shfl(sidx, j + 2 * p + h);
    g[p] = *(const __half2*)(tab + (size_t)s * D + 2 * m);
  }
}

__device__ __forceinline__ void gather_consume(
    float w, int h, int j, const __half2* g, float* ax, float* ay) {
#pragma unroll
  for (int p = 0; p < 8; ++p) {
    float wp = __shfl(w, j + 2 * p + h);
    ax[p] = fmaf(wp, __low2float(g[p]), ax[p]);
    ay[p] = fmaf(wp, __high2float(g[p]), ay[p]);
  }
}

__device__ __forceinline__ float csr_gather_h2(
    const int* __restrict__ src, const float* __restrict__ nrm,
    const __half* __restrict__ tab, int e0, int e1, int lane,
    int pidx, float pw) {
  int h = lane >> 5;
  int m = lane & 31;
  float ax[8], ay[8];
#pragma unroll
  for (int p = 0; p < 8; ++p) { ax[p] = 0.0f; ay[p] = 0.0f; }
  bool first = true;
  for (int base = e0; base < e1; base += 64) {
    int cnt = e1 - base; if (cnt > 64) cnt = 64;
    int sidx; float w;
    if (first) {
      sidx = pidx; w = pw;
    } else {
      sidx = 0; w = 0.0f;
      if (lane < cnt) {
        sidx = src[base + lane];
        w = nrm ? nrm[base + lane] : 1.0f;
      }
    }
    first = false;
    int jend = (cnt + 15) & ~15;
    __half2 v[8], u[8];
    gather_issue(tab, sidx, h, m, 0, v);
    int j = 0;
    while (true) {
      if (j + 16 < jend) gather_issue(tab, sidx, h, m, j + 16, u);
      gather_consume(w, h, j, v, ax, ay);
      j += 16;
      if (j >= jend) break;
      if (j + 16 < jend) gather_issue(tab, sidx, h, m, j + 16, v);
      gather_consume(w, h, j, u, ax, ay);
      j += 16;
      if (j >= jend) break;
    }
  }
  float sx = ((ax[0] + ax[1]) + (ax[2] + ax[3])) + ((ax[4] + ax[5]) + (ax[6] + ax[7]));
  float sy = ((ay[0] + ay[1]) + (ay[2] + ay[3])) + ((ay[4] + ay[5]) + (ay[6] + ay[7]));
  sx += __shfl_xor(sx, 32);
  sy += __shfl_xor(sy, 32);
  float ev = __shfl(sx, lane >> 1);
  float od = __shfl(sy, lane >> 1);
  return (lane & 1) ? od : ev;
}

// ---------------- dense input FC: y = relu(LN(x @ W + b)) -> fp16 ----------
__global__ __launch_bounds__(256) void fc_in_kernel(
    const float* __restrict__ x, const float* __restrict__ W,
    const float* __restrict__ b, const float* __restrict__ s,
    const float* __restrict__ beta, __half* __restrict__ y, int n) {
  int wid = (int)(((size_t)blockIdx.x * blockDim.x + threadIdx.x) >> 6);
  int lane = threadIdx.x & 63;
  if (wid >= n) return;
  const float* xr = x + (size_t)wid * DIN;
  float v0 = xr[lane];
  float v1 = xr[64 + lane];
  float acc = b[lane];
#pragma unroll
  for (int k = 0; k < 64; ++k)
    acc = fmaf(__shfl(v0, k), W[k * 64 + lane], acc);
#pragma unroll
  for (int k = 0; k < 64; ++k)
    acc = fmaf(__shfl(v1, k), W[(k + 64) * 64 + lane], acc);
  float m = wave_sum64(acc) * (1.0f / 64.0f);
  float d = acc - m;
  float var = wave_sum64(d * d) * (1.0f / 64.0f);
  float o = d * rsqrtf(var + LN_EPS) * s[lane] + beta[lane];
  y[(size_t)wid * D + lane] = __float2half(fmaxf(o, 0.0f));
}

// =============== atomic-free CSR build: 2-level counting sort ===============
// R1: per-block LDS histogram of bucket (= key>>10); bhist[bkt][blk], btot[bkt]
__global__ __launch_bounds__(256) void r1_hist_kernel(
    const int* __restrict__ ei_gg, const int* __restrict__ ei_cg,
    const int* __restrict__ ei_cc, int* __restrict__ bhist,
    int* __restrict__ btot) {
  __shared__ int hist[256];
  int t = threadIdx.x;
  int k = blockIdx.x;
  hist[t] = 0;
  __syncthreads();
  int base = k * EPB;
  for (int i = t; i < EPB; i += 256) {
    int e = base + i;
    if (e >= E_ALL) break;
    int key;
    if (e < EGG) key = ei_gg[EGG + e];
    else if (e < EGG + ECG) key = NG + ei_cg[ECG + (e - EGG)];
    else key = 2 * NG + ei_cc[ECC + (e - EGG - ECG)];
    atomicAdd(&hist[key >> 10], 1);
  }
  __syncthreads();
  if (t < NBKT) {
    bhist[t * NBLK + k] = hist[t];
    atomicAdd(&btot[t], hist[t]);
  }
}

// R2b: exclusive scan of bucket totals -> bbase[0..NBKT]; S[SCAN_N] = E_ALL
__global__ __launch_bounds__(256) void r2b_kernel(
    const int* __restrict__ btot, int* __restrict__ bbase,
    int* __restrict__ S) {
  __shared__ int sh[256];
  int t = threadIdx.x;
  int v = (t < NBKT) ? btot[t] : 0;
  sh[t] = v;
  __syncthreads();
#pragma unroll
  for (int off = 1; off < 256; off <<= 1) {
    int u = (t >= off) ? sh[t - off] : 0;
    __syncthreads();
    sh[t] += u;
    __syncthreads();
  }
  if (t < NBKT) bbase[t] = sh[t] - v;
  if (t == 255) { bbase[NBKT] = sh[255]; S[SCAN_N] = sh[255]; }
}

// R2c: per-bucket scan over blocks: base[b][k] = bbase[b] + prefix_k(bhist[b])
__global__ __launch_bounds__(512) void r2c_kernel(
    const int* __restrict__ bhist, const int* __restrict__ bbase,
    int* __restrict__ base) {
  int b = blockIdx.x;
  int t = threadIdx.x;
  int lane = t & 63, wv = t >> 6;
  int v = bhist[b * NBLK + t];
  int sc = v;
#pragma unroll
  for (int off = 1; off < 64; off <<= 1) {
    int u = __shfl_up(sc, off);
    if (lane >= off) sc += u;
  }
  __shared__ int ws[8];
  if (lane == 63) ws[wv] = sc;
  __syncthreads();
  int wb = 0;
  for (int i = 0; i < wv; ++i) wb += ws[i];
  base[b * NBLK + t] = bbase[b] + wb + sc - v;
}

// R3: scatter edges into bucket-grouped arrays (LDS cursors, no global atomics)
__global__ __launch_bounds__(256) void r3_scatter_kernel(
    const int* __restrict__ ei_gg, const float* __restrict__ ew_gg,
    const int* __restrict__ ei_cg, const int* __restrict__ ei_cc,
    const int* __restrict__ base, int* __restrict__ ksort,
    int* __restrict__ ssort, float* __restrict__ wsort) {
  __shared__ int cur[256];
  int t = threadIdx.x;
  int k = blockIdx.x;
  if (t < NBKT) cur[t] = base[t * NBLK + k];
  __syncthreads();
  int bb = k * EPB;
  for (int i = t; i < EPB; i += 256) {
    int e = bb + i;
    if (e >= E_ALL) break;
    int key, s; float w = 0.0f; bool isg = false;
    if (e < EGG) {
      key = ei_gg[EGG + e]; s = ei_gg[e]; w = ew_gg[e]; isg = true;
    } else if (e < EGG + ECG) {
      int q = e - EGG; key = NG + ei_cg[ECG + q]; s = ei_cg[q];
    } else {
      int q = e - EGG - ECG; key = 2 * NG + ei_cc[ECC + q]; s = ei_cc[q];
    }
    int p = atomicAdd(&cur[key >> 10], 1);   // LDS atomic
    ksort[p] = key;
    ssort[p] = s;
    if (isg) wsort[p] = w;                   // gg keys sort first: p < EGG
  }
}

// R4: per-bucket 1024-bin counting sort -> S (row ptrs) + srcbuf + ewp
__global__ __launch_bounds__(1024) void r4_sort_kernel(
    const int* __restrict__ ksort, const int* __restrict__ ssort,
    const float* __restrict__ wsort, const int* __restrict__ bbase,
    int* __restrict__ S, int* __restrict__ srcbuf, float* __restrict__ ewp) {
  int b = blockIdx.x;
  int t = threadIdx.x;
  int e0 = bbase[b], e1 = bbase[b + 1];
  int kbase = b << 10;
  __shared__ int hist[1024];
  __shared__ int sh[1024];
  __shared__ int cur[1024];
  hist[t] = 0;
  __syncthreads();
  for (int e = e0 + t; e < e1; e += 1024)
    atomicAdd(&hist[ksort[e] - kbase], 1);
  __syncthreads();
  int c = hist[t];
  sh[t] = c;
  __syncthreads();
#pragma unroll
  for (int off = 1; off < 1024; off <<= 1) {
    int u = (t >= off) ? sh[t - off] : 0;
    __syncthreads();
    sh[t] += u;
    __syncthreads();
  }
  int ex = e0 + sh[t] - c;     // global exclusive prefix for key kbase+t
  int key = kbase + t;
  if (key < SCAN_N) S[key] = ex;
  cur[t] = ex;
  __syncthreads();
  for (int e = e0 + t; e < e1; e += 1024) {
    int k2 = ksort[e];
    int p = atomicAdd(&cur[k2 - kbase], 1);
    srcbuf[p] = ssort[e];
    if (k2 < NG) ewp[p] = wsort[e];
  }
}

// dinv[i] = rsqrt(1 + segment sum of permuted edge weights)
__global__ __launch_bounds__(256) void deg_kernel(
    const int* __restrict__ S, const float* __restrict__ ewp,
    float* __restrict__ dinv) {
  int i = (int)(((size_t)blockIdx.x * blockDim.x + threadIdx.x) >> 6);
  int lane = threadIdx.x & 63;
  if (i >= NG) return;
  int e0 = S[i], e1 = S[i + 1];
  float s = 0.0f;
  for (int e = e0 + lane; e < e1; e += 64) s += ewp[e];
  s = wave_sum64(s);
  if (lane == 0) dinv[i] = rsqrtf(s + 1.0f);
}

// nrm[e] = dinv[src] * ew * dinv[dst]
__global__ __launch_bounds__(256) void nrm_kernel(
    const int* __restrict__ S, const int* __restrict__ srcbuf,
    const float* __restrict__ ewp, const float* __restrict__ dinv,
    float* __restrict__ nrm) {
  int i = (int)(((size_t)blockIdx.x * blockDim.x + threadIdx.x) >> 6);
  int lane = threadIdx.x & 63;
  if (i >= NG) return;
  float di = dinv[i];
  int e0 = S[i], e1 = S[i + 1];
  for (int e = e0 + lane; e < e1; e += 64)
    nrm[e] = dinv[srcbuf[e]] * ewp[e] * di;
}

// ---------------- fused glom layer -----------------------------------------
__global__ __launch_bounds__(256) void glom_layer_kernel(
    const int* __restrict__ rp_gg, const int* __restrict__ rp_cg,
    const int* __restrict__ srcbuf, const float* __restrict__ nrm_gg,
    const __half* __restrict__ xg_old, const __half* __restrict__ xc_old,
    const float* __restrict__ dinv,
    const float* __restrict__ W_gcn, const float* __restrict__ b_gcn,
    const float* __restrict__ eps_cg, const float* __restrict__ W_cg,
    const float* __restrict__ b_cg,
    const float* __restrict__ ls, const float* __restrict__ lb,
    __half* __restrict__ xg_new, int n) {
  int i = (int)(((size_t)blockIdx.x * blockDim.x + threadIdx.x) >> 6);
  int lane = threadIdx.x & 63;
  if (i >= n) return;
  int ge0 = rp_gg[i], ge1 = rp_gg[i + 1];
  int fe0 = rp_cg[i], fe1 = rp_cg[i + 1];
  int gidx = 0; float gw = 0.0f;
  if (ge0 + lane < ge1) { gidx = srcbuf[ge0 + lane]; gw = nrm_gg[ge0 + lane]; }
  int cidx = 0; float cw = 0.0f;
  if (fe0 + lane < fe1) { cidx = srcbuf[fe0 + lane]; cw = 1.0f; }
  float self = __half2float(xg_old[(size_t)i * D + lane]);
  float di = dinv[i];
  float accG = di * di * self
             + csr_gather_h2(srcbuf, nrm_gg, xg_old, ge0, ge1, lane, gidx, gw);
  float accC = csr_gather_h2(srcbuf, nullptr, xc_old, fe0, fe1, lane, cidx, cw);
  float gcn = b_gcn[lane];
#pragma unroll
  for (int k = 0; k < 64; ++k)
    gcn = fmaf(__shfl(accG, k), W_gcn[k * 64 + lane], gcn);
  float h = (1.0f + eps_cg[0]) * self + accC;
  float gin = b_cg[lane];
#pragma unroll
  for (int k = 0; k < 64; ++k)
    gin = fmaf(__shfl(h, k), W_cg[k * 64 + lane], gin);
  float g = gcn + fmaxf(gin, 0.0f);
  float m = wave_sum64(g) * (1.0f / 64.0f);
  float d = g - m;
  float var = wave_sum64(d * d) * (1.0f / 64.0f);
  float o = d * rsqrtf(var + LN_EPS) * ls[lane] + lb[lane];
  xg_new[(size_t)i * D + lane] = __float2half(fmaxf(o, 0.0f));
}

// ---------------- fused cell layer -----------------------------------------
__global__ __launch_bounds__(256) void cell_layer_kernel(
    const int* __restrict__ rp_cc, const int* __restrict__ srcbuf,
    const __half* __restrict__ xc_old,
    const float* __restrict__ eps_cc, const float* __restrict__ W_cc,
    const float* __restrict__ b_cc,
    const float* __restrict__ ls, const float* __restrict__ lb,
    __half* __restrict__ xc_new, int n) {
  int i = (int)(((size_t)blockIdx.x * blockDim.x + threadIdx.x) >> 6);
  int lane = threadIdx.x & 63;
  if (i >= n) return;
  int e0 = rp_cc[i], e1 = rp_cc[i + 1];
  int cidx = 0; float cw = 0.0f;
  if (e0 + lane < e1) { cidx = srcbuf[e0 + lane]; cw = 1.0f; }
  float self = __half2float(xc_old[(size_t)i * D + lane]);
  float acc = csr_gather_h2(srcbuf, nullptr, xc_old, e0, e1, lane, cidx, cw);
  float h = (1.0f + eps_cc[0]) * self + acc;
  float gin = b_cc[lane];
#pragma unroll
  for (int k = 0; k < 64; ++k)
    gin = fmaf(__shfl(h, k), W_cc[k * 64 + lane], gin);
  float g = fmaxf(gin, 0.0f);
  float m = wave_sum64(g) * (1.0f / 64.0f);
  float d = g - m;
  float var = wave_sum64(d * d) * (1.0f / 64.0f);
  float o = d * rsqrtf(var + LN_EPS) * ls[lane] + lb[lane];
  xc_new[(size_t)i * D + lane] = __float2half(fmaxf(o, 0.0f));
}

// ---------------- output head: wave per row --------------------------------
__global__ __launch_bounds__(256) void out_kernel(
    const __half* __restrict__ xg, const float* __restrict__ W,
    const float* __restrict__ b, float* __restrict__ out, int n) {
  int wid = (int)(((size_t)blockIdx.x * blockDim.x + threadIdx.x) >> 6);
  int lane = threadIdx.x & 63;
  if (wid >= n) return;
  float v = __half2float(xg[(size_t)wid * D + lane]);
  float a0 = wave_sum64(v * W[lane * 3 + 0]) + b[0];
  float a1 = wave_sum64(v * W[lane * 3 + 1]) + b[1];
  float a2 = wave_sum64(v * W[lane * 3 + 2]) + b[2];
  float m = fmaxf(a0, fmaxf(a1, a2));
  float e0 = expf(a0 - m), e1 = expf(a1 - m), e2 = expf(a2 - m);
  float inv = 1.0f / (e0 + e1 + e2);
  if (lane == 0) {
    out[(size_t)wid * 3 + 0] = e0 * inv;
    out[(size_t)wid * 3 + 1] = e1 * inv;
    out[(size_t)wid * 3 + 2] = e2 * inv;
  }
}

extern "C" void kernel_launch(void* const* d_in, const int* in_sizes, int n_in,
                              void* d_out, int out_size, void* d_ws, size_t ws_size,
                              hipStream_t stream) {
  const float* x_glom = (const float*)d_in[0];
  const float* x_cell = (const float*)d_in[1];
  const int*   ei_gg  = (const int*)d_in[2];
  const float* ew_gg  = (const float*)d_in[3];
  const int*   ei_cg  = (const int*)d_in[4];
  const int*   ei_cc  = (const int*)d_in[5];
  const float* W_in_g = (const float*)d_in[6];
  const float* b_in_g = (const float*)d_in[7];
  const float* lnig_s = (const float*)d_in[8];
  const float* lnig_b = (const float*)d_in[9];
  const float* W_in_c = (const float*)d_in[10];
  const float* b_in_c = (const float*)d_in[11];
  const float* lnic_s = (const float*)d_in[12];
  const float* lnic_b = (const float*)d_in[13];
  const float* W_outp = (const float*)d_in[34];
  const float* b_outp = (const float*)d_in[35];

  // ---- workspace layout ----
  char* P = (char*)d_ws;
  __half* xg0 = (__half*)P;                    P += (size_t)NG * D * 2;   // 6.4 MB
  __half* xg1 = (__half*)P;                    P += (size_t)NG * D * 2;   // 6.4 MB
  __half* xc0 = (__half*)P;                    P += (size_t)NC * D * 2;   // 12.8 MB
  __half* xc1 = (__half*)P;                    P += (size_t)NC * D * 2;   // 12.8 MB
  float* dinv = (float*)P;                     P += (size_t)NG * 4;
  float* nrm  = (float*)P;                     P += (size_t)EGG * 4;
  int* S      = (int*)P;                       P += (size_t)(SCAN_N + 1) * 4;
  int* srcbuf = (int*)P;                       P += (size_t)E_ALL * 4;    // 16 MB
  int* bhist  = (int*)P;                       P += (size_t)NBKT * NBLK * 4;
  int* base   = (int*)P;                       P += (size_t)NBKT * NBLK * 4;
  int* btot   = (int*)P;                       P += (size_t)NBKT * 4;
  int* bbase  = (int*)P;                       P += (size_t)(NBKT + 1) * 4;
  // transients over the feature-table region (dead before fc_in writes it):
  // ksort 16MB | ssort 16MB | wsort 3.2MB | ewp 3.2MB = 38.4MB == tables size
  int* ksort   = (int*)d_ws;
  int* ssort   = ksort + E_ALL;
  float* wsort = (float*)(ssort + E_ALL);
  float* ewp   = wsort + EGG;

  dim3 blk(256);
  auto wgrid = [](long long waves) { return dim3((unsigned)((waves + 3) / 4)); };

  // ---- CSR build: atomic-free two-level counting sort ----
  hipMemsetAsync(btot, 0, NBKT * sizeof(int), stream);
  r1_hist_kernel<<<dim3(NBLK), blk, 0, stream>>>(ei_gg, ei_cg, ei_cc, bhist, btot);
  r2b_kernel<<<dim3(1), dim3(256), 0, stream>>>(btot, bbase, S);
  r2c_kernel<<<dim3(NBKT), dim3(512), 0, stream>>>(bhist, bbase, base);
  r3_scatter_kernel<<<dim3(NBLK), blk, 0, stream>>>(
      ei_gg, ew_gg, ei_cg, ei_cc, base, ksort, ssort, wsort);
  r4_sort_kernel<<<dim3(NBKT), dim3(1024), 0, stream>>>(
      ksort, ssort, wsort, bbase, S, srcbuf, ewp);
  deg_kernel<<<wgrid(NG), blk, 0, stream>>>(S, ewp, dinv);
  nrm_kernel<<<wgrid(NG), blk, 0, stream>>>(S, srcbuf, ewp, dinv, nrm);

  // ---- input FCs (overwrite the transient ksort/ssort/wsort/ewp region) ----
  fc_in_kernel<<<wgrid(NG), blk, 0, stream>>>(x_glom, W_in_g, b_in_g, lnig_s, lnig_b, xg0, NG);
  fc_in_kernel<<<wgrid(NC), blk, 0, stream>>>(x_cell, W_in_c, b_in_c, lnic_s, lnic_b, xc0, NC);

  // ---- two hetero MP layers (double-buffered) ----
  const int* rp_gg = S;
  const int* rp_cg = S + NG;
  const int* rp_cc = S + 2 * NG;
  __half* xg_cur = xg0; __half* xg_nxt = xg1;
  __half* xc_cur = xc0; __half* xc_nxt = xc1;
  for (int l = 0; l < 2; ++l) {
    const float* const* p = (const float* const*)(d_in + 14 + 10 * l);
    const float* W_gcn = p[0]; const float* b_gcn = p[1];
    const float* eps_cg = p[2]; const float* W_cg = p[3]; const float* b_cg = p[4];
    const float* eps_cc = p[5]; const float* W_cc = p[6]; const float* b_cc = p[7];
    const float* ln_s = p[8]; const float* ln_b = p[9];

    glom_layer_kernel<<<wgrid(NG), blk, 0, stream>>>(
        rp_gg, rp_cg, srcbuf, nrm, xg_cur, xc_cur, dinv,
        W_gcn, b_gcn, eps_cg, W_cg, b_cg, ln_s, ln_b, xg_nxt, NG);
    cell_layer_kernel<<<wgrid(NC), blk, 0, stream>>>(
        rp_cc, srcbuf, xc_cur, eps_cc, W_cc, b_cc, ln_s, ln_b, xc_nxt, NC);

    __half* t;
    t = xg_cur; xg_cur = xg_nxt; xg_nxt = t;
    t = xc_cur; xc_cur = xc_nxt; xc_nxt = t;
  }

  out_kernel<<<wgrid(NG), blk, 0, stream>>>(xg_cur, W_outp, b_outp, (float*)d_out, NG);
}

// Round 10
// 738.636 us; speedup vs baseline: 1.2811x; 1.1069x over previous
//
#include <hip/hip_runtime.h>
#include <hip/hip_fp16.h>

#define NG 50000
#define NC 100000
#define DIN 128
#define D 64
#define EGG 800000
#define ECG 1600000
#define ECC 1600000
#define LN_EPS 1e-5f

#define SCAN_N (2 * NG + NC)            // 200000 keys: gg dst | cg dst | cc dst
#define E_ALL (EGG + ECG + ECC)         // 4,000,000 edges
#define NBKT 196                        // buckets of 1024 keys (199999>>10 = 195)
#define NBLK 512                        // blocks in R1/R3
#define EPB ((E_ALL + NBLK - 1) / NBLK) // edges per block = 7813

__device__ __forceinline__ float wave_sum64(float v) {
#pragma unroll
  for (int off = 32; off > 0; off >>= 1) v += __shfl_xor(v, off);
  return v;
}

// ---- pipelined fp16 CSR gather ---------------------------------------------
__device__ __forceinline__ void gather_issue(
    const __half* __restrict__ tab, int sidx, int h, int m, int j,
    __half2* g) {
#pragma unroll
  for (int p = 0; p < 8; ++p) {
    int s = __shfl(sidx, j + 2 * p + h);
    g[p] = *(const __half2*)(tab + (size_t)s * D + 2 * m);
  }
}

__device__ __forceinline__ void gather_consume(
    float w, int h, int j, const __half2* g, float* ax, float* ay) {
#pragma unroll
  for (int p = 0; p < 8; ++p) {
    float wp = __shfl(w, j + 2 * p + h);
    ax[p] = fmaf(wp, __low2float(g[p]), ax[p]);
    ay[p] = fmaf(wp, __high2float(g[p]), ay[p]);
  }
}

__device__ __forceinline__ float csr_gather_h2(
    const int* __restrict__ src, const float* __restrict__ nrm,
    const __half* __restrict__ tab, int e0, int e1, int lane,
    int pidx, float pw) {
  int h = lane >> 5;
  int m = lane & 31;
  float ax[8], ay[8];
#pragma unroll
  for (int p = 0; p < 8; ++p) { ax[p] = 0.0f; ay[p] = 0.0f; }
  bool first = true;
  for (int base = e0; base < e1; base += 64) {
    int cnt = e1 - base; if (cnt > 64) cnt = 64;
    int sidx; float w;
    if (first) {
      sidx = pidx; w = pw;
    } else {
      sidx = 0; w = 0.0f;
      if (lane < cnt) {
        sidx = src[base + lane];
        w = nrm ? nrm[base + lane] : 1.0f;
      }
    }
    first = false;
    int jend = (cnt + 15) & ~15;
    __half2 v[8], u[8];
    gather_issue(tab, sidx, h, m, 0, v);
    int j = 0;
    while (true) {
      if (j + 16 < jend) gather_issue(tab, sidx, h, m, j + 16, u);
      gather_consume(w, h, j, v, ax, ay);
      j += 16;
      if (j >= jend) break;
      if (j + 16 < jend) gather_issue(tab, sidx, h, m, j + 16, v);
      gather_consume(w, h, j, u, ax, ay);
      j += 16;
      if (j >= jend) break;
    }
  }
  float sx = ((ax[0] + ax[1]) + (ax[2] + ax[3])) + ((ax[4] + ax[5]) + (ax[6] + ax[7]));
  float sy = ((ay[0] + ay[1]) + (ay[2] + ay[3])) + ((ay[4] + ay[5]) + (ay[6] + ay[7]));
  sx += __shfl_xor(sx, 32);
  sy += __shfl_xor(sy, 32);
  float ev = __shfl(sx, lane >> 1);
  float od = __shfl(sy, lane >> 1);
  return (lane & 1) ? od : ev;
}

// ---------------- dense input FC: y = relu(LN(x @ W + b)) -> fp16 ----------
// x-row address is wave-uniform: force scalar (s_load) reads of x[k] via
// readfirstlane -> no ds_bpermute broadcasts at all (the old __shfl version
// was LDS-pipe-bound at ~165us/dispatch).
__global__ __launch_bounds__(256) void fc_in_kernel(
    const float* __restrict__ x, const float* __restrict__ W,
    const float* __restrict__ b, const float* __restrict__ s,
    const float* __restrict__ beta, __half* __restrict__ y, int n) {
  int wid = (int)(((size_t)blockIdx.x * blockDim.x + threadIdx.x) >> 6);
  int lane = threadIdx.x & 63;
  if (wid >= n) return;
  int row = __builtin_amdgcn_readfirstlane(wid);
  const float* xr = x + (size_t)row * DIN;   // uniform pointer -> s_load
  float acc0 = b[lane];
  float acc1 = 0.0f;
#pragma unroll
  for (int k = 0; k < 128; k += 2) {
    acc0 = fmaf(xr[k],     W[k * 64 + lane],       acc0);
    acc1 = fmaf(xr[k + 1], W[(k + 1) * 64 + lane], acc1);
  }
  float acc = acc0 + acc1;
  float m = wave_sum64(acc) * (1.0f / 64.0f);
  float d = acc - m;
  float var = wave_sum64(d * d) * (1.0f / 64.0f);
  float o = d * rsqrtf(var + LN_EPS) * s[lane] + beta[lane];
  y[(size_t)row * D + lane] = __float2half(fmaxf(o, 0.0f));
}

// =============== atomic-free CSR build: 2-level counting sort ===============
__global__ __launch_bounds__(256) void r1_hist_kernel(
    const int* __restrict__ ei_gg, const int* __restrict__ ei_cg,
    const int* __restrict__ ei_cc, int* __restrict__ bhist,
    int* __restrict__ btot) {
  __shared__ int hist[256];
  int t = threadIdx.x;
  int k = blockIdx.x;
  hist[t] = 0;
  __syncthreads();
  int base = k * EPB;
  for (int i = t; i < EPB; i += 256) {
    int e = base + i;
    if (e >= E_ALL) break;
    int key;
    if (e < EGG) key = ei_gg[EGG + e];
    else if (e < EGG + ECG) key = NG + ei_cg[ECG + (e - EGG)];
    else key = 2 * NG + ei_cc[ECC + (e - EGG - ECG)];
    atomicAdd(&hist[key >> 10], 1);
  }
  __syncthreads();
  if (t < NBKT) {
    bhist[t * NBLK + k] = hist[t];
    atomicAdd(&btot[t], hist[t]);
  }
}

__global__ __launch_bounds__(256) void r2b_kernel(
    const int* __restrict__ btot, int* __restrict__ bbase,
    int* __restrict__ S) {
  __shared__ int sh[256];
  int t = threadIdx.x;
  int v = (t < NBKT) ? btot[t] : 0;
  sh[t] = v;
  __syncthreads();
#pragma unroll
  for (int off = 1; off < 256; off <<= 1) {
    int u = (t >= off) ? sh[t - off] : 0;
    __syncthreads();
    sh[t] += u;
    __syncthreads();
  }
  if (t < NBKT) bbase[t] = sh[t] - v;
  if (t == 255) { bbase[NBKT] = sh[255]; S[SCAN_N] = sh[255]; }
}

__global__ __launch_bounds__(512) void r2c_kernel(
    const int* __restrict__ bhist, const int* __restrict__ bbase,
    int* __restrict__ base) {
  int b = blockIdx.x;
  int t = threadIdx.x;
  int lane = t & 63, wv = t >> 6;
  int v = bhist[b * NBLK + t];
  int sc = v;
#pragma unroll
  for (int off = 1; off < 64; off <<= 1) {
    int u = __shfl_up(sc, off);
    if (lane >= off) sc += u;
  }
  __shared__ int ws[8];
  if (lane == 63) ws[wv] = sc;
  __syncthreads();
  int wb = 0;
  for (int i = 0; i < wv; ++i) wb += ws[i];
  base[b * NBLK + t] = bbase[b] + wb + sc - v;
}

__global__ __launch_bounds__(256) void r3_scatter_kernel(
    const int* __restrict__ ei_gg, const float* __restrict__ ew_gg,
    const int* __restrict__ ei_cg, const int* __restrict__ ei_cc,
    const int* __restrict__ base, int* __restrict__ ksort,
    int* __restrict__ ssort, float* __restrict__ wsort) {
  __shared__ int cur[256];
  int t = threadIdx.x;
  int k = blockIdx.x;
  if (t < NBKT) cur[t] = base[t * NBLK + k];
  __syncthreads();
  int bb = k * EPB;
  for (int i = t; i < EPB; i += 256) {
    int e = bb + i;
    if (e >= E_ALL) break;
    int key, s; float w = 0.0f; bool isg = false;
    if (e < EGG) {
      key = ei_gg[EGG + e]; s = ei_gg[e]; w = ew_gg[e]; isg = true;
    } else if (e < EGG + ECG) {
      int q = e - EGG; key = NG + ei_cg[ECG + q]; s = ei_cg[q];
    } else {
      int q = e - EGG - ECG; key = 2 * NG + ei_cc[ECC + q]; s = ei_cc[q];
    }
    int p = atomicAdd(&cur[key >> 10], 1);   // LDS atomic
    ksort[p] = key;
    ssort[p] = s;
    if (isg) wsort[p] = w;
  }
}

__global__ __launch_bounds__(1024) void r4_sort_kernel(
    const int* __restrict__ ksort, const int* __restrict__ ssort,
    const float* __restrict__ wsort, const int* __restrict__ bbase,
    int* __restrict__ S, int* __restrict__ srcbuf, float* __restrict__ ewp) {
  int b = blockIdx.x;
  int t = threadIdx.x;
  int e0 = bbase[b], e1 = bbase[b + 1];
  int kbase = b << 10;
  __shared__ int hist[1024];
  __shared__ int sh[1024];
  __shared__ int cur[1024];
  hist[t] = 0;
  __syncthreads();
  for (int e = e0 + t; e < e1; e += 1024)
    atomicAdd(&hist[ksort[e] - kbase], 1);
  __syncthreads();
  int c = hist[t];
  sh[t] = c;
  __syncthreads();
#pragma unroll
  for (int off = 1; off < 1024; off <<= 1) {
    int u = (t >= off) ? sh[t - off] : 0;
    __syncthreads();
    sh[t] += u;
    __syncthreads();
  }
  int ex = e0 + sh[t] - c;
  int key = kbase + t;
  if (key < SCAN_N) S[key] = ex;
  cur[t] = ex;
  __syncthreads();
  for (int e = e0 + t; e < e1; e += 1024) {
    int k2 = ksort[e];
    int p = atomicAdd(&cur[k2 - kbase], 1);
    srcbuf[p] = ssort[e];
    if (k2 < NG) ewp[p] = wsort[e];
  }
}

__global__ __launch_bounds__(256) void deg_kernel(
    const int* __restrict__ S, const float* __restrict__ ewp,
    float* __restrict__ dinv) {
  int i = (int)(((size_t)blockIdx.x * blockDim.x + threadIdx.x) >> 6);
  int lane = threadIdx.x & 63;
  if (i >= NG) return;
  int e0 = S[i], e1 = S[i + 1];
  float s = 0.0f;
  for (int e = e0 + lane; e < e1; e += 64) s += ewp[e];
  s = wave_sum64(s);
  if (lane == 0) dinv[i] = rsqrtf(s + 1.0f);
}

__global__ __launch_bounds__(256) void nrm_kernel(
    const int* __restrict__ S, const int* __restrict__ srcbuf,
    const float* __restrict__ ewp, const float* __restrict__ dinv,
    float* __restrict__ nrm) {
  int i = (int)(((size_t)blockIdx.x * blockDim.x + threadIdx.x) >> 6);
  int lane = threadIdx.x & 63;
  if (i >= NG) return;
  float di = dinv[i];
  int e0 = S[i], e1 = S[i + 1];
  for (int e = e0 + lane; e < e1; e += 64)
    nrm[e] = dinv[srcbuf[e]] * ewp[e] * di;
}

// ---------------- fused glom layer -----------------------------------------
__global__ __launch_bounds__(256) void glom_layer_kernel(
    const int* __restrict__ rp_gg, const int* __restrict__ rp_cg,
    const int* __restrict__ srcbuf, const float* __restrict__ nrm_gg,
    const __half* __restrict__ xg_old, const __half* __restrict__ xc_old,
    const float* __restrict__ dinv,
    const float* __restrict__ W_gcn, const float* __restrict__ b_gcn,
    const float* __restrict__ eps_cg, const float* __restrict__ W_cg,
    const float* __restrict__ b_cg,
    const float* __restrict__ ls, const float* __restrict__ lb,
    __half* __restrict__ xg_new, int n) {
  int i = (int)(((size_t)blockIdx.x * blockDim.x + threadIdx.x) >> 6);
  int lane = threadIdx.x & 63;
  if (i >= n) return;
  int ge0 = rp_gg[i], ge1 = rp_gg[i + 1];
  int fe0 = rp_cg[i], fe1 = rp_cg[i + 1];
  int gidx = 0; float gw = 0.0f;
  if (ge0 + lane < ge1) { gidx = srcbuf[ge0 + lane]; gw = nrm_gg[ge0 + lane]; }
  int cidx = 0; float cw = 0.0f;
  if (fe0 + lane < fe1) { cidx = srcbuf[fe0 + lane]; cw = 1.0f; }
  float self = __half2float(xg_old[(size_t)i * D + lane]);
  float di = dinv[i];
  float accG = di * di * self
             + csr_gather_h2(srcbuf, nrm_gg, xg_old, ge0, ge1, lane, gidx, gw);
  float accC = csr_gather_h2(srcbuf, nullptr, xc_old, fe0, fe1, lane, cidx, cw);
  float gcn = b_gcn[lane];
#pragma unroll
  for (int k = 0; k < 64; ++k)
    gcn = fmaf(__shfl(accG, k), W_gcn[k * 64 + lane], gcn);
  float h = (1.0f + eps_cg[0]) * self + accC;
  float gin = b_cg[lane];
#pragma unroll
  for (int k = 0; k < 64; ++k)
    gin = fmaf(__shfl(h, k), W_cg[k * 64 + lane], gin);
  float g = gcn + fmaxf(gin, 0.0f);
  float m = wave_sum64(g) * (1.0f / 64.0f);
  float d = g - m;
  float var = wave_sum64(d * d) * (1.0f / 64.0f);
  float o = d * rsqrtf(var + LN_EPS) * ls[lane] + lb[lane];
  xg_new[(size_t)i * D + lane] = __float2half(fmaxf(o, 0.0f));
}

// ---------------- fused cell layer -----------------------------------------
__global__ __launch_bounds__(256) void cell_layer_kernel(
    const int* __restrict__ rp_cc, const int* __restrict__ srcbuf,
    const __half* __restrict__ xc_old,
    const float* __restrict__ eps_cc, const float* __restrict__ W_cc,
    const float* __restrict__ b_cc,
    const float* __restrict__ ls, const float* __restrict__ lb,
    __half* __restrict__ xc_new, int n) {
  int i = (int)(((size_t)blockIdx.x * blockDim.x + threadIdx.x) >> 6);
  int lane = threadIdx.x & 63;
  if (i >= n) return;
  int e0 = rp_cc[i], e1 = rp_cc[i + 1];
  int cidx = 0; float cw = 0.0f;
  if (e0 + lane < e1) { cidx = srcbuf[e0 + lane]; cw = 1.0f; }
  float self = __half2float(xc_old[(size_t)i * D + lane]);
  float acc = csr_gather_h2(srcbuf, nullptr, xc_old, e0, e1, lane, cidx, cw);
  float h = (1.0f + eps_cc[0]) * self + acc;
  float gin = b_cc[lane];
#pragma unroll
  for (int k = 0; k < 64; ++k)
    gin = fmaf(__shfl(h, k), W_cc[k * 64 + lane], gin);
  float g = fmaxf(gin, 0.0f);
  float m = wave_sum64(g) * (1.0f / 64.0f);
  float d = g - m;
  float var = wave_sum64(d * d) * (1.0f / 64.0f);
  float o = d * rsqrtf(var + LN_EPS) * ls[lane] + lb[lane];
  xc_new[(size_t)i * D + lane] = __float2half(fmaxf(o, 0.0f));
}

// ---------------- output head: wave per row --------------------------------
__global__ __launch_bounds__(256) void out_kernel(
    const __half* __restrict__ xg, const float* __restrict__ W,
    const float* __restrict__ b, float* __restrict__ out, int n) {
  int wid = (int)(((size_t)blockIdx.x * blockDim.x + threadIdx.x) >> 6);
  int lane = threadIdx.x & 63;
  if (wid >= n) return;
  float v = __half2float(xg[(size_t)wid * D + lane]);
  float a0 = wave_sum64(v * W[lane * 3 + 0]) + b[0];
  float a1 = wave_sum64(v * W[lane * 3 + 1]) + b[1];
  float a2 = wave_sum64(v * W[lane * 3 + 2]) + b[2];
  float m = fmaxf(a0, fmaxf(a1, a2));
  float e0 = expf(a0 - m), e1 = expf(a1 - m), e2 = expf(a2 - m);
  float inv = 1.0f / (e0 + e1 + e2);
  if (lane == 0) {
    out[(size_t)wid * 3 + 0] = e0 * inv;
    out[(size_t)wid * 3 + 1] = e1 * inv;
    out[(size_t)wid * 3 + 2] = e2 * inv;
  }
}

extern "C" void kernel_launch(void* const* d_in, const int* in_sizes, int n_in,
                              void* d_out, int out_size, void* d_ws, size_t ws_size,
                              hipStream_t stream) {
  const float* x_glom = (const float*)d_in[0];
  const float* x_cell = (const float*)d_in[1];
  const int*   ei_gg  = (const int*)d_in[2];
  const float* ew_gg  = (const float*)d_in[3];
  const int*   ei_cg  = (const int*)d_in[4];
  const int*   ei_cc  = (const int*)d_in[5];
  const float* W_in_g = (const float*)d_in[6];
  const float* b_in_g = (const float*)d_in[7];
  const float* lnig_s = (const float*)d_in[8];
  const float* lnig_b = (const float*)d_in[9];
  const float* W_in_c = (const float*)d_in[10];
  const float* b_in_c = (const float*)d_in[11];
  const float* lnic_s = (const float*)d_in[12];
  const float* lnic_b = (const float*)d_in[13];
  const float* W_outp = (const float*)d_in[34];
  const float* b_outp = (const float*)d_in[35];

  // ---- workspace layout ----
  char* P = (char*)d_ws;
  __half* xg0 = (__half*)P;                    P += (size_t)NG * D * 2;
  __half* xg1 = (__half*)P;                    P += (size_t)NG * D * 2;
  __half* xc0 = (__half*)P;                    P += (size_t)NC * D * 2;
  __half* xc1 = (__half*)P;                    P += (size_t)NC * D * 2;
  float* dinv = (float*)P;                     P += (size_t)NG * 4;
  float* nrm  = (float*)P;                     P += (size_t)EGG * 4;
  int* S      = (int*)P;                       P += (size_t)(SCAN_N + 1) * 4;
  int* srcbuf = (int*)P;                       P += (size_t)E_ALL * 4;
  int* bhist  = (int*)P;                       P += (size_t)NBKT * NBLK * 4;
  int* base   = (int*)P;                       P += (size_t)NBKT * NBLK * 4;
  int* btot   = (int*)P;                       P += (size_t)NBKT * 4;
  int* bbase  = (int*)P;                       P += (size_t)(NBKT + 1) * 4;
  // transients over the feature-table region (dead before fc_in writes it)
  int* ksort   = (int*)d_ws;
  int* ssort   = ksort + E_ALL;
  float* wsort = (float*)(ssort + E_ALL);
  float* ewp   = wsort + EGG;

  dim3 blk(256);
  auto wgrid = [](long long waves) { return dim3((unsigned)((waves + 3) / 4)); };

  // ---- CSR build: atomic-free two-level counting sort ----
  hipMemsetAsync(btot, 0, NBKT * sizeof(int), stream);
  r1_hist_kernel<<<dim3(NBLK), blk, 0, stream>>>(ei_gg, ei_cg, ei_cc, bhist, btot);
  r2b_kernel<<<dim3(1), dim3(256), 0, stream>>>(btot, bbase, S);
  r2c_kernel<<<dim3(NBKT), dim3(512), 0, stream>>>(bhist, bbase, base);
  r3_scatter_kernel<<<dim3(NBLK), blk, 0, stream>>>(
      ei_gg, ew_gg, ei_cg, ei_cc, base, ksort, ssort, wsort);
  r4_sort_kernel<<<dim3(NBKT), dim3(1024), 0, stream>>>(
      ksort, ssort, wsort, bbase, S, srcbuf, ewp);
  deg_kernel<<<wgrid(NG), blk, 0, stream>>>(S, ewp, dinv);
  nrm_kernel<<<wgrid(NG), blk, 0, stream>>>(S, srcbuf, ewp, dinv, nrm);

  // ---- input FCs (overwrite the transient ksort/ssort/wsort/ewp region) ----
  fc_in_kernel<<<wgrid(NG), blk, 0, stream>>>(x_glom, W_in_g, b_in_g, lnig_s, lnig_b, xg0, NG);
  fc_in_kernel<<<wgrid(NC), blk, 0, stream>>>(x_cell, W_in_c, b_in_c, lnic_s, lnic_b, xc0, NC);

  // ---- two hetero MP layers (double-buffered) ----
  const int* rp_gg = S;
  const int* rp_cg = S + NG;
  const int* rp_cc = S + 2 * NG;
  __half* xg_cur = xg0; __half* xg_nxt = xg1;
  __half* xc_cur = xc0; __half* xc_nxt = xc1;
  for (int l = 0; l < 2; ++l) {
    const float* const* p = (const float* const*)(d_in + 14 + 10 * l);
    const float* W_gcn = p[0]; const float* b_gcn = p[1];
    const float* eps_cg = p[2]; const float* W_cg = p[3]; const float* b_cg = p[4];
    const float* eps_cc = p[5]; const float* W_cc = p[6]; const float* b_cc = p[7];
    const float* ln_s = p[8]; const float* ln_b = p[9];

    glom_layer_kernel<<<wgrid(NG), blk, 0, stream>>>(
        rp_gg, rp_cg, srcbuf, nrm, xg_cur, xc_cur, dinv,
        W_gcn, b_gcn, eps_cg, W_cg, b_cg, ln_s, ln_b, xg_nxt, NG);
    cell_layer_kernel<<<wgrid(NC), blk, 0, stream>>>(
        rp_cc, srcbuf, xc_cur, eps_cc, W_cc, b_cc, ln_s, ln_b, xc_nxt, NC);

    __half* t;
    t = xg_cur; xg_cur = xg_nxt; xg_nxt = t;
    t = xc_cur; xc_cur = xc_nxt; xc_nxt = t;
  }

  out_kernel<<<wgrid(NG), blk, 0, stream>>>(xg_cur, W_outp, b_outp, (float*)d_out, NG);
}

// Round 11
// 710.029 us; speedup vs baseline: 1.3327x; 1.0403x over previous
//
#include <hip/hip_runtime.h>
#include <hip/hip_fp16.h>

#define NG 50000
#define NC 100000
#define DIN 128
#define D 64
#define EGG 800000
#define ECG 1600000
#define ECC 1600000
#define LN_EPS 1e-5f

#define SCAN_N (2 * NG + NC)            // 200000 keys: gg dst | cg dst | cc dst
#define E_ALL (EGG + ECG + ECC)         // 4,000,000 edges
#define NBKT 196                        // buckets of 1024 keys
#define NBLK 512                        // blocks in R1/R3
#define EPB ((E_ALL + NBLK - 1) / NBLK) // edges per block = 7813

__device__ __forceinline__ float wave_sum64(float v) {
#pragma unroll
  for (int off = 32; off > 0; off >>= 1) v += __shfl_xor(v, off);
  return v;
}

// ---- pipelined fp16 CSR gather ---------------------------------------------
__device__ __forceinline__ void gather_issue(
    const __half* __restrict__ tab, int sidx, int h, int m, int j,
    __half2* g) {
#pragma unroll
  for (int p = 0; p < 8; ++p) {
    int s = __shfl(sidx, j + 2 * p + h);
    g[p] = *(const __half2*)(tab + (size_t)s * D + 2 * m);
  }
}

__device__ __forceinline__ void gather_consume(
    float w, int h, int j, const __half2* g, float* ax, float* ay) {
#pragma unroll
  for (int p = 0; p < 8; ++p) {
    float wp = __shfl(w, j + 2 * p + h);
    ax[p] = fmaf(wp, __low2float(g[p]), ax[p]);
    ay[p] = fmaf(wp, __high2float(g[p]), ay[p]);
  }
}

__device__ __forceinline__ float csr_gather_h2(
    const int* __restrict__ src, const float* __restrict__ nrm,
    const __half* __restrict__ tab, int e0, int e1, int lane,
    int pidx, float pw) {
  int h = lane >> 5;
  int m = lane & 31;
  float ax[8], ay[8];
#pragma unroll
  for (int p = 0; p < 8; ++p) { ax[p] = 0.0f; ay[p] = 0.0f; }
  bool first = true;
  for (int base = e0; base < e1; base += 64) {
    int cnt = e1 - base; if (cnt > 64) cnt = 64;
    int sidx; float w;
    if (first) {
      sidx = pidx; w = pw;
    } else {
      sidx = 0; w = 0.0f;
      if (lane < cnt) {
        sidx = src[base + lane];
        w = nrm ? nrm[base + lane] : 1.0f;
      }
    }
    first = false;
    int jend = (cnt + 15) & ~15;
    __half2 v[8], u[8];
    gather_issue(tab, sidx, h, m, 0, v);
    int j = 0;
    while (true) {
      if (j + 16 < jend) gather_issue(tab, sidx, h, m, j + 16, u);
      gather_consume(w, h, j, v, ax, ay);
      j += 16;
      if (j >= jend) break;
      if (j + 16 < jend) gather_issue(tab, sidx, h, m, j + 16, v);
      gather_consume(w, h, j, u, ax, ay);
      j += 16;
      if (j >= jend) break;
    }
  }
  float sx = ((ax[0] + ax[1]) + (ax[2] + ax[3])) + ((ax[4] + ax[5]) + (ax[6] + ax[7]));
  float sy = ((ay[0] + ay[1]) + (ay[2] + ay[3])) + ((ay[4] + ay[5]) + (ay[6] + ay[7]));
  sx += __shfl_xor(sx, 32);
  sy += __shfl_xor(sy, 32);
  float ev = __shfl(sx, lane >> 1);
  float od = __shfl(sy, lane >> 1);
  return (lane & 1) ? od : ev;
}

// ---------------- dense input FC: 4 rows per wave ---------------------------
// Scalar (s_load) x reads; W[k*64+lane] loaded once per k, used for 4 FMAs
// -> W L1 traffic /4 vs 1-row version.
__global__ __launch_bounds__(256) void fc_in_kernel(
    const float* __restrict__ x, const float* __restrict__ W,
    const float* __restrict__ b, const float* __restrict__ s,
    const float* __restrict__ beta, __half* __restrict__ y, int n) {
  int wid = (int)(((size_t)blockIdx.x * blockDim.x + threadIdx.x) >> 6);
  int lane = threadIdx.x & 63;
  int r0 = __builtin_amdgcn_readfirstlane(wid) * 4;
  if (r0 >= n) return;
  int nr = n - r0; if (nr > 4) nr = 4;
  const float* xr0 = x + (size_t)r0 * DIN;
  const float* xr1 = xr0 + ((nr > 1) ? DIN : 0);
  const float* xr2 = xr0 + ((nr > 2) ? 2 * DIN : 0);
  const float* xr3 = xr0 + ((nr > 3) ? 3 * DIN : 0);
  float bl = b[lane];
  float a0 = bl, a1 = bl, a2 = bl, a3 = bl;
#pragma unroll
  for (int k = 0; k < 128; ++k) {
    float wk = W[k * 64 + lane];
    a0 = fmaf(xr0[k], wk, a0);
    a1 = fmaf(xr1[k], wk, a1);
    a2 = fmaf(xr2[k], wk, a2);
    a3 = fmaf(xr3[k], wk, a3);
  }
  float sl = s[lane], bb = beta[lane];
  float acc[4] = {a0, a1, a2, a3};
#pragma unroll
  for (int r = 0; r < 4; ++r) {
    if (r >= nr) break;
    float m = wave_sum64(acc[r]) * (1.0f / 64.0f);
    float d = acc[r] - m;
    float var = wave_sum64(d * d) * (1.0f / 64.0f);
    float o = d * rsqrtf(var + LN_EPS) * sl + bb;
    y[(size_t)(r0 + r) * D + lane] = __float2half(fmaxf(o, 0.0f));
  }
}

// =============== atomic-free CSR build: 2-level counting sort ===============
__global__ __launch_bounds__(256) void r1_hist_kernel(
    const int* __restrict__ ei_gg, const int* __restrict__ ei_cg,
    const int* __restrict__ ei_cc, int* __restrict__ bhist,
    int* __restrict__ btot) {
  __shared__ int hist[256];
  int t = threadIdx.x;
  int k = blockIdx.x;
  hist[t] = 0;
  __syncthreads();
  int base = k * EPB;
  for (int i = t; i < EPB; i += 256) {
    int e = base + i;
    if (e >= E_ALL) break;
    int key;
    if (e < EGG) key = ei_gg[EGG + e];
    else if (e < EGG + ECG) key = NG + ei_cg[ECG + (e - EGG)];
    else key = 2 * NG + ei_cc[ECC + (e - EGG - ECG)];
    atomicAdd(&hist[key >> 10], 1);
  }
  __syncthreads();
  if (t < NBKT) {
    bhist[t * NBLK + k] = hist[t];
    atomicAdd(&btot[t], hist[t]);
  }
}

__global__ __launch_bounds__(256) void r2b_kernel(
    const int* __restrict__ btot, int* __restrict__ bbase,
    int* __restrict__ S) {
  __shared__ int sh[256];
  int t = threadIdx.x;
  int v = (t < NBKT) ? btot[t] : 0;
  sh[t] = v;
  __syncthreads();
#pragma unroll
  for (int off = 1; off < 256; off <<= 1) {
    int u = (t >= off) ? sh[t - off] : 0;
    __syncthreads();
    sh[t] += u;
    __syncthreads();
  }
  if (t < NBKT) bbase[t] = sh[t] - v;
  if (t == 255) { bbase[NBKT] = sh[255]; S[SCAN_N] = sh[255]; }
}

__global__ __launch_bounds__(512) void r2c_kernel(
    const int* __restrict__ bhist, const int* __restrict__ bbase,
    int* __restrict__ base) {
  int b = blockIdx.x;
  int t = threadIdx.x;
  int lane = t & 63, wv = t >> 6;
  int v = bhist[b * NBLK + t];
  int sc = v;
#pragma unroll
  for (int off = 1; off < 64; off <<= 1) {
    int u = __shfl_up(sc, off);
    if (lane >= off) sc += u;
  }
  __shared__ int ws[8];
  if (lane == 63) ws[wv] = sc;
  __syncthreads();
  int wb = 0;
  for (int i = 0; i < wv; ++i) wb += ws[i];
  base[b * NBLK + t] = bbase[b] + wb + sc - v;
}

// R3: scatter packed (localkey<<17 | src) records; wsort only at gg positions.
__global__ __launch_bounds__(256) void r3_scatter_kernel(
    const int* __restrict__ ei_gg, const float* __restrict__ ew_gg,
    const int* __restrict__ ei_cg, const int* __restrict__ ei_cc,
    const int* __restrict__ base, int* __restrict__ ssort,
    float* __restrict__ wsort) {
  __shared__ int cur[256];
  int t = threadIdx.x;
  int k = blockIdx.x;
  if (t < NBKT) cur[t] = base[t * NBLK + k];
  __syncthreads();
  int bb = k * EPB;
  for (int i = t; i < EPB; i += 256) {
    int e = bb + i;
    if (e >= E_ALL) break;
    int key, s; float w = 0.0f; bool isg = false;
    if (e < EGG) {
      key = ei_gg[EGG + e]; s = ei_gg[e]; w = ew_gg[e]; isg = true;
    } else if (e < EGG + ECG) {
      int q = e - EGG; key = NG + ei_cg[ECG + q]; s = ei_cg[q];
    } else {
      int q = e - EGG - ECG; key = 2 * NG + ei_cc[ECC + q]; s = ei_cc[q];
    }
    int p = atomicAdd(&cur[key >> 10], 1);   // LDS atomic
    ssort[p] = ((key & 1023) << 17) | s;     // src < 2^17
    if (isg) wsort[p] = w;
  }
}

// R4: per-bucket 1024-bin counting sort of packed records
__global__ __launch_bounds__(1024) void r4_sort_kernel(
    const int* __restrict__ ssort, const float* __restrict__ wsort,
    const int* __restrict__ bbase, int* __restrict__ S,
    int* __restrict__ srcbuf, float* __restrict__ ewp) {
  int b = blockIdx.x;
  int t = threadIdx.x;
  int e0 = bbase[b], e1 = bbase[b + 1];
  int kbase = b << 10;
  __shared__ int hist[1024];
  __shared__ int sh[1024];
  __shared__ int cur[1024];
  hist[t] = 0;
  __syncthreads();
  for (int e = e0 + t; e < e1; e += 1024)
    atomicAdd(&hist[((unsigned)ssort[e]) >> 17], 1);
  __syncthreads();
  int c = hist[t];
  sh[t] = c;
  __syncthreads();
#pragma unroll
  for (int off = 1; off < 1024; off <<= 1) {
    int u = (t >= off) ? sh[t - off] : 0;
    __syncthreads();
    sh[t] += u;
    __syncthreads();
  }
  int ex = e0 + sh[t] - c;
  int key = kbase + t;
  if (key < SCAN_N) S[key] = ex;
  cur[t] = ex;
  __syncthreads();
  for (int e = e0 + t; e < e1; e += 1024) {
    int rec = ssort[e];
    int lk = ((unsigned)rec) >> 17;
    int p = atomicAdd(&cur[lk], 1);
    srcbuf[p] = rec & 0x1FFFF;
    if (kbase + lk < NG) ewp[p] = wsort[e];
  }
}

__global__ __launch_bounds__(256) void deg_kernel(
    const int* __restrict__ S, const float* __restrict__ ewp,
    float* __restrict__ dinv) {
  int i = (int)(((size_t)blockIdx.x * blockDim.x + threadIdx.x) >> 6);
  int lane = threadIdx.x & 63;
  if (i >= NG) return;
  int e0 = S[i], e1 = S[i + 1];
  float s = 0.0f;
  for (int e = e0 + lane; e < e1; e += 64) s += ewp[e];
  s = wave_sum64(s);
  if (lane == 0) dinv[i] = rsqrtf(s + 1.0f);
}

__global__ __launch_bounds__(256) void nrm_kernel(
    const int* __restrict__ S, const int* __restrict__ srcbuf,
    const float* __restrict__ ewp, const float* __restrict__ dinv,
    float* __restrict__ nrm) {
  int i = (int)(((size_t)blockIdx.x * blockDim.x + threadIdx.x) >> 6);
  int lane = threadIdx.x & 63;
  if (i >= NG) return;
  float di = dinv[i];
  int e0 = S[i], e1 = S[i + 1];
  for (int e = e0 + lane; e < e1; e += 64)
    nrm[e] = dinv[srcbuf[e]] * ewp[e] * di;
}

// ---------------- merged hetero layer: row<NG -> glom, else cell ------------
__global__ __launch_bounds__(256) void layer_kernel(
    const int* __restrict__ S, const int* __restrict__ srcbuf,
    const float* __restrict__ nrm_gg,
    const __half* __restrict__ xg_old, const __half* __restrict__ xc_old,
    const float* __restrict__ dinv,
    const float* __restrict__ W_gcn, const float* __restrict__ b_gcn,
    const float* __restrict__ eps_cg, const float* __restrict__ W_cg,
    const float* __restrict__ b_cg,
    const float* __restrict__ eps_cc, const float* __restrict__ W_cc,
    const float* __restrict__ b_cc,
    const float* __restrict__ ls, const float* __restrict__ lb,
    __half* __restrict__ xg_new, __half* __restrict__ xc_new) {
  int row = (int)(((size_t)blockIdx.x * blockDim.x + threadIdx.x) >> 6);
  int lane = threadIdx.x & 63;
  if (row >= NG + NC) return;

  float g;       // pre-LN value for this row/dim
  if (row < NG) {
    int i = row;
    const int* rp_gg = S;
    const int* rp_cg = S + NG;
    int ge0 = rp_gg[i], ge1 = rp_gg[i + 1];
    int fe0 = rp_cg[i], fe1 = rp_cg[i + 1];
    int gidx = 0; float gw = 0.0f;
    if (ge0 + lane < ge1) { gidx = srcbuf[ge0 + lane]; gw = nrm_gg[ge0 + lane]; }
    int cidx = 0; float cw = 0.0f;
    if (fe0 + lane < fe1) { cidx = srcbuf[fe0 + lane]; cw = 1.0f; }
    float self = __half2float(xg_old[(size_t)i * D + lane]);
    float di = dinv[i];
    float accG = di * di * self
               + csr_gather_h2(srcbuf, nrm_gg, xg_old, ge0, ge1, lane, gidx, gw);
    float accC = csr_gather_h2(srcbuf, nullptr, xc_old, fe0, fe1, lane, cidx, cw);
    float gcn = b_gcn[lane];
#pragma unroll
    for (int k = 0; k < 64; ++k)
      gcn = fmaf(__shfl(accG, k), W_gcn[k * 64 + lane], gcn);
    float h = (1.0f + eps_cg[0]) * self + accC;
    float gin = b_cg[lane];
#pragma unroll
    for (int k = 0; k < 64; ++k)
      gin = fmaf(__shfl(h, k), W_cg[k * 64 + lane], gin);
    g = gcn + fmaxf(gin, 0.0f);
  } else {
    int i = row - NG;
    const int* rp_cc = S + 2 * NG;
    int e0 = rp_cc[i], e1 = rp_cc[i + 1];
    int cidx = 0; float cw = 0.0f;
    if (e0 + lane < e1) { cidx = srcbuf[e0 + lane]; cw = 1.0f; }
    float self = __half2float(xc_old[(size_t)i * D + lane]);
    float acc = csr_gather_h2(srcbuf, nullptr, xc_old, e0, e1, lane, cidx, cw);
    float h = (1.0f + eps_cc[0]) * self + acc;
    float gin = b_cc[lane];
#pragma unroll
    for (int k = 0; k < 64; ++k)
      gin = fmaf(__shfl(h, k), W_cc[k * 64 + lane], gin);
    g = fmaxf(gin, 0.0f);
  }

  float m = wave_sum64(g) * (1.0f / 64.0f);
  float d = g - m;
  float var = wave_sum64(d * d) * (1.0f / 64.0f);
  float o = d * rsqrtf(var + LN_EPS) * ls[lane] + lb[lane];
  __half val = __float2half(fmaxf(o, 0.0f));
  if (row < NG) xg_new[(size_t)row * D + lane] = val;
  else xc_new[(size_t)(row - NG) * D + lane] = val;
}

// ---------------- output head: wave per row --------------------------------
__global__ __launch_bounds__(256) void out_kernel(
    const __half* __restrict__ xg, const float* __restrict__ W,
    const float* __restrict__ b, float* __restrict__ out, int n) {
  int wid = (int)(((size_t)blockIdx.x * blockDim.x + threadIdx.x) >> 6);
  int lane = threadIdx.x & 63;
  if (wid >= n) return;
  float v = __half2float(xg[(size_t)wid * D + lane]);
  float a0 = wave_sum64(v * W[lane * 3 + 0]) + b[0];
  float a1 = wave_sum64(v * W[lane * 3 + 1]) + b[1];
  float a2 = wave_sum64(v * W[lane * 3 + 2]) + b[2];
  float m = fmaxf(a0, fmaxf(a1, a2));
  float e0 = expf(a0 - m), e1 = expf(a1 - m), e2 = expf(a2 - m);
  float inv = 1.0f / (e0 + e1 + e2);
  if (lane == 0) {
    out[(size_t)wid * 3 + 0] = e0 * inv;
    out[(size_t)wid * 3 + 1] = e1 * inv;
    out[(size_t)wid * 3 + 2] = e2 * inv;
  }
}

extern "C" void kernel_launch(void* const* d_in, const int* in_sizes, int n_in,
                              void* d_out, int out_size, void* d_ws, size_t ws_size,
                              hipStream_t stream) {
  const float* x_glom = (const float*)d_in[0];
  const float* x_cell = (const float*)d_in[1];
  const int*   ei_gg  = (const int*)d_in[2];
  const float* ew_gg  = (const float*)d_in[3];
  const int*   ei_cg  = (const int*)d_in[4];
  const int*   ei_cc  = (const int*)d_in[5];
  const float* W_in_g = (const float*)d_in[6];
  const float* b_in_g = (const float*)d_in[7];
  const float* lnig_s = (const float*)d_in[8];
  const float* lnig_b = (const float*)d_in[9];
  const float* W_in_c = (const float*)d_in[10];
  const float* b_in_c = (const float*)d_in[11];
  const float* lnic_s = (const float*)d_in[12];
  const float* lnic_b = (const float*)d_in[13];
  const float* W_outp = (const float*)d_in[34];
  const float* b_outp = (const float*)d_in[35];

  // ---- workspace layout ----
  char* P = (char*)d_ws;
  __half* xg0 = (__half*)P;                    P += (size_t)NG * D * 2;
  __half* xg1 = (__half*)P;                    P += (size_t)NG * D * 2;
  __half* xc0 = (__half*)P;                    P += (size_t)NC * D * 2;
  __half* xc1 = (__half*)P;                    P += (size_t)NC * D * 2;
  float* dinv = (float*)P;                     P += (size_t)NG * 4;
  float* nrm  = (float*)P;                     P += (size_t)EGG * 4;
  int* S      = (int*)P;                       P += (size_t)(SCAN_N + 1) * 4;
  int* srcbuf = (int*)P;                       P += (size_t)E_ALL * 4;
  int* bhist  = (int*)P;                       P += (size_t)NBKT * NBLK * 4;
  int* base   = (int*)P;                       P += (size_t)NBKT * NBLK * 4;
  int* btot   = (int*)P;                       P += (size_t)NBKT * 4;
  int* bbase  = (int*)P;                       P += (size_t)(NBKT + 1) * 4;
  // transients over the feature-table region (dead before fc_in writes it):
  // ssort 16MB | wsort 3.2MB | ewp 3.2MB = 22.4MB < 38.4MB tables
  int* ssort   = (int*)d_ws;
  float* wsort = (float*)(ssort + E_ALL);
  float* ewp   = wsort + EGG;

  dim3 blk(256);
  auto wgrid = [](long long waves) { return dim3((unsigned)((waves + 3) / 4)); };

  // ---- CSR build: atomic-free two-level counting sort ----
  hipMemsetAsync(btot, 0, NBKT * sizeof(int), stream);
  r1_hist_kernel<<<dim3(NBLK), blk, 0, stream>>>(ei_gg, ei_cg, ei_cc, bhist, btot);
  r2b_kernel<<<dim3(1), dim3(256), 0, stream>>>(btot, bbase, S);
  r2c_kernel<<<dim3(NBKT), dim3(512), 0, stream>>>(bhist, bbase, base);
  r3_scatter_kernel<<<dim3(NBLK), blk, 0, stream>>>(
      ei_gg, ew_gg, ei_cg, ei_cc, base, ssort, wsort);
  r4_sort_kernel<<<dim3(NBKT), dim3(1024), 0, stream>>>(
      ssort, wsort, bbase, S, srcbuf, ewp);
  deg_kernel<<<wgrid(NG), blk, 0, stream>>>(S, ewp, dinv);
  nrm_kernel<<<wgrid(NG), blk, 0, stream>>>(S, srcbuf, ewp, dinv, nrm);

  // ---- input FCs (overwrite the transient ssort/wsort/ewp region) ----
  fc_in_kernel<<<wgrid((NG + 3) / 4), blk, 0, stream>>>(
      x_glom, W_in_g, b_in_g, lnig_s, lnig_b, xg0, NG);
  fc_in_kernel<<<wgrid((NC + 3) / 4), blk, 0, stream>>>(
      x_cell, W_in_c, b_in_c, lnic_s, lnic_b, xc0, NC);

  // ---- two hetero MP layers (merged glom+cell dispatch, double-buffered) ----
  __half* xg_cur = xg0; __half* xg_nxt = xg1;
  __half* xc_cur = xc0; __half* xc_nxt = xc1;
  for (int l = 0; l < 2; ++l) {
    const float* const* p = (const float* const*)(d_in + 14 + 10 * l);
    const float* W_gcn = p[0]; const float* b_gcn = p[1];
    const float* eps_cg = p[2]; const float* W_cg = p[3]; const float* b_cg = p[4];
    const float* eps_cc = p[5]; const float* W_cc = p[6]; const float* b_cc = p[7];
    const float* ln_s = p[8]; const float* ln_b = p[9];

    layer_kernel<<<wgrid(NG + NC), blk, 0, stream>>>(
        S, srcbuf, nrm, xg_cur, xc_cur, dinv,
        W_gcn, b_gcn, eps_cg, W_cg, b_cg, eps_cc, W_cc, b_cc,
        ln_s, ln_b, xg_nxt, xc_nxt);

    __half* t;
    t = xg_cur; xg_cur = xg_nxt; xg_nxt = t;
    t = xc_cur; xc_cur = xc_nxt; xc_nxt = t;
  }

  out_kernel<<<wgrid(NG), blk, 0, stream>>>(xg_cur, W_outp, b_outp, (float*)d_out, NG);
}

// Round 12
// 593.165 us; speedup vs baseline: 1.5953x; 1.1970x over previous
//
#include <hip/hip_runtime.h>
#include <hip/hip_fp16.h>

#define NG 50000
#define NC 100000
#define DIN 128
#define D 64
#define EGG 800000
#define ECG 1600000
#define ECC 1600000
#define LN_EPS 1e-5f

#define SCAN_N (2 * NG + NC)            // 200000 keys: gg dst | cg dst | cc dst
#define E_ALL (EGG + ECG + ECC)         // 4,000,000 edges
#define NBKT 196                        // buckets of 1024 keys
#define NBLK 512                        // blocks in R1/R3
#define EPB ((E_ALL + NBLK - 1) / NBLK) // edges per block = 7813

__device__ __forceinline__ float wave_sum64(float v) {
#pragma unroll
  for (int off = 32; off > 0; off >>= 1) v += __shfl_xor(v, off);
  return v;
}

__device__ __forceinline__ float bcast_lane(float v, int k) {
  // compile-time k -> v_readlane_b32 (VALU), NOT ds_bpermute (DS pipe)
  return __int_as_float(__builtin_amdgcn_readlane(__float_as_int(v), k));
}

// ---- scalar-indexed fp16 CSR gather ----------------------------------------
// e0/e1 MUST be wave-uniform SGPR values (caller readfirstlanes them).
// Indices & weights load via the SCALAR pipe (s_load: uniform ptr + uniform
// idx); each row read is one global_load_ushort per lane (lane = dim,
// 128B coalesced). No DS-pipe ops, no cross-lane redistribution.
__device__ __forceinline__ float csr_gather_s(
    const int* __restrict__ src, const float* __restrict__ nrm,
    const __half* __restrict__ tab, int e0, int e1, int lane) {
  float a0 = 0.f, a1 = 0.f, a2 = 0.f, a3 = 0.f;
  int e = e0;
  for (; e + 8 <= e1; e += 8) {
    int s0 = src[e + 0], s1 = src[e + 1], s2 = src[e + 2], s3 = src[e + 3];
    int s4 = src[e + 4], s5 = src[e + 5], s6 = src[e + 6], s7 = src[e + 7];
    __half v0 = tab[(size_t)s0 * D + lane];
    __half v1 = tab[(size_t)s1 * D + lane];
    __half v2 = tab[(size_t)s2 * D + lane];
    __half v3 = tab[(size_t)s3 * D + lane];
    __half v4 = tab[(size_t)s4 * D + lane];
    __half v5 = tab[(size_t)s5 * D + lane];
    __half v6 = tab[(size_t)s6 * D + lane];
    __half v7 = tab[(size_t)s7 * D + lane];
    if (nrm) {
      a0 = fmaf(nrm[e + 0], __half2float(v0), a0);
      a1 = fmaf(nrm[e + 1], __half2float(v1), a1);
      a2 = fmaf(nrm[e + 2], __half2float(v2), a2);
      a3 = fmaf(nrm[e + 3], __half2float(v3), a3);
      a0 = fmaf(nrm[e + 4], __half2float(v4), a0);
      a1 = fmaf(nrm[e + 5], __half2float(v5), a1);
      a2 = fmaf(nrm[e + 6], __half2float(v6), a2);
      a3 = fmaf(nrm[e + 7], __half2float(v7), a3);
    } else {
      a0 += __half2float(v0); a1 += __half2float(v1);
      a2 += __half2float(v2); a3 += __half2float(v3);
      a0 += __half2float(v4); a1 += __half2float(v5);
      a2 += __half2float(v6); a3 += __half2float(v7);
    }
  }
  for (; e < e1; ++e) {
    int s = src[e];
    float v = __half2float(tab[(size_t)s * D + lane]);
    if (nrm) a0 = fmaf(nrm[e], v, a0); else a0 += v;
  }
  return (a0 + a1) + (a2 + a3);
}

// ---------------- dense input FC: 4 rows per wave ---------------------------
__global__ __launch_bounds__(256) void fc_in_kernel(
    const float* __restrict__ x, const float* __restrict__ W,
    const float* __restrict__ b, const float* __restrict__ s,
    const float* __restrict__ beta, __half* __restrict__ y, int n) {
  int wid = (int)(((size_t)blockIdx.x * blockDim.x + threadIdx.x) >> 6);
  int lane = threadIdx.x & 63;
  int r0 = __builtin_amdgcn_readfirstlane(wid) * 4;
  if (r0 >= n) return;
  int nr = n - r0; if (nr > 4) nr = 4;
  const float* xr0 = x + (size_t)r0 * DIN;
  const float* xr1 = xr0 + ((nr > 1) ? DIN : 0);
  const float* xr2 = xr0 + ((nr > 2) ? 2 * DIN : 0);
  const float* xr3 = xr0 + ((nr > 3) ? 3 * DIN : 0);
  float bl = b[lane];
  float a0 = bl, a1 = bl, a2 = bl, a3 = bl;
#pragma unroll
  for (int k = 0; k < 128; ++k) {
    float wk = W[k * 64 + lane];
    a0 = fmaf(xr0[k], wk, a0);
    a1 = fmaf(xr1[k], wk, a1);
    a2 = fmaf(xr2[k], wk, a2);
    a3 = fmaf(xr3[k], wk, a3);
  }
  float sl = s[lane], bb = beta[lane];
  float acc[4] = {a0, a1, a2, a3};
#pragma unroll
  for (int r = 0; r < 4; ++r) {
    if (r >= nr) break;
    float m = wave_sum64(acc[r]) * (1.0f / 64.0f);
    float d = acc[r] - m;
    float var = wave_sum64(d * d) * (1.0f / 64.0f);
    float o = d * rsqrtf(var + LN_EPS) * sl + bb;
    y[(size_t)(r0 + r) * D + lane] = __float2half(fmaxf(o, 0.0f));
  }
}

// =============== atomic-free CSR build: 2-level counting sort ===============
__global__ __launch_bounds__(256) void r1_hist_kernel(
    const int* __restrict__ ei_gg, const int* __restrict__ ei_cg,
    const int* __restrict__ ei_cc, int* __restrict__ bhist,
    int* __restrict__ btot) {
  __shared__ int hist[256];
  int t = threadIdx.x;
  int k = blockIdx.x;
  hist[t] = 0;
  __syncthreads();
  int base = k * EPB;
  for (int i = t; i < EPB; i += 256) {
    int e = base + i;
    if (e >= E_ALL) break;
    int key;
    if (e < EGG) key = ei_gg[EGG + e];
    else if (e < EGG + ECG) key = NG + ei_cg[ECG + (e - EGG)];
    else key = 2 * NG + ei_cc[ECC + (e - EGG - ECG)];
    atomicAdd(&hist[key >> 10], 1);
  }
  __syncthreads();
  if (t < NBKT) {
    bhist[t * NBLK + k] = hist[t];
    atomicAdd(&btot[t], hist[t]);
  }
}

__global__ __launch_bounds__(256) void r2b_kernel(
    const int* __restrict__ btot, int* __restrict__ bbase,
    int* __restrict__ S) {
  __shared__ int sh[256];
  int t = threadIdx.x;
  int v = (t < NBKT) ? btot[t] : 0;
  sh[t] = v;
  __syncthreads();
#pragma unroll
  for (int off = 1; off < 256; off <<= 1) {
    int u = (t >= off) ? sh[t - off] : 0;
    __syncthreads();
    sh[t] += u;
    __syncthreads();
  }
  if (t < NBKT) bbase[t] = sh[t] - v;
  if (t == 255) { bbase[NBKT] = sh[255]; S[SCAN_N] = sh[255]; }
}

__global__ __launch_bounds__(512) void r2c_kernel(
    const int* __restrict__ bhist, const int* __restrict__ bbase,
    int* __restrict__ base) {
  int b = blockIdx.x;
  int t = threadIdx.x;
  int lane = t & 63, wv = t >> 6;
  int v = bhist[b * NBLK + t];
  int sc = v;
#pragma unroll
  for (int off = 1; off < 64; off <<= 1) {
    int u = __shfl_up(sc, off);
    if (lane >= off) sc += u;
  }
  __shared__ int ws[8];
  if (lane == 63) ws[wv] = sc;
  __syncthreads();
  int wb = 0;
  for (int i = 0; i < wv; ++i) wb += ws[i];
  base[b * NBLK + t] = bbase[b] + wb + sc - v;
}

__global__ __launch_bounds__(256) void r3_scatter_kernel(
    const int* __restrict__ ei_gg, const float* __restrict__ ew_gg,
    const int* __restrict__ ei_cg, const int* __restrict__ ei_cc,
    const int* __restrict__ base, int* __restrict__ ssort,
    float* __restrict__ wsort) {
  __shared__ int cur[256];
  int t = threadIdx.x;
  int k = blockIdx.x;
  if (t < NBKT) cur[t] = base[t * NBLK + k];
  __syncthreads();
  int bb = k * EPB;
  for (int i = t; i < EPB; i += 256) {
    int e = bb + i;
    if (e >= E_ALL) break;
    int key, s; float w = 0.0f; bool isg = false;
    if (e < EGG) {
      key = ei_gg[EGG + e]; s = ei_gg[e]; w = ew_gg[e]; isg = true;
    } else if (e < EGG + ECG) {
      int q = e - EGG; key = NG + ei_cg[ECG + q]; s = ei_cg[q];
    } else {
      int q = e - EGG - ECG; key = 2 * NG + ei_cc[ECC + q]; s = ei_cc[q];
    }
    int p = atomicAdd(&cur[key >> 10], 1);   // LDS atomic
    ssort[p] = ((key & 1023) << 17) | s;     // src < 2^17
    if (isg) wsort[p] = w;
  }
}

__global__ __launch_bounds__(1024) void r4_sort_kernel(
    const int* __restrict__ ssort, const float* __restrict__ wsort,
    const int* __restrict__ bbase, int* __restrict__ S,
    int* __restrict__ srcbuf, float* __restrict__ ewp) {
  int b = blockIdx.x;
  int t = threadIdx.x;
  int e0 = bbase[b], e1 = bbase[b + 1];
  int kbase = b << 10;
  __shared__ int hist[1024];
  __shared__ int sh[1024];
  __shared__ int cur[1024];
  hist[t] = 0;
  __syncthreads();
  for (int e = e0 + t; e < e1; e += 1024)
    atomicAdd(&hist[((unsigned)ssort[e]) >> 17], 1);
  __syncthreads();
  int c = hist[t];
  sh[t] = c;
  __syncthreads();
#pragma unroll
  for (int off = 1; off < 1024; off <<= 1) {
    int u = (t >= off) ? sh[t - off] : 0;
    __syncthreads();
    sh[t] += u;
    __syncthreads();
  }
  int ex = e0 + sh[t] - c;
  int key = kbase + t;
  if (key < SCAN_N) S[key] = ex;
  cur[t] = ex;
  __syncthreads();
  for (int e = e0 + t; e < e1; e += 1024) {
    int rec = ssort[e];
    int lk = ((unsigned)rec) >> 17;
    int p = atomicAdd(&cur[lk], 1);
    srcbuf[p] = rec & 0x1FFFF;
    if (kbase + lk < NG) ewp[p] = wsort[e];
  }
}

__global__ __launch_bounds__(256) void deg_kernel(
    const int* __restrict__ S, const float* __restrict__ ewp,
    float* __restrict__ dinv) {
  int i = (int)(((size_t)blockIdx.x * blockDim.x + threadIdx.x) >> 6);
  int lane = threadIdx.x & 63;
  if (i >= NG) return;
  int e0 = S[i], e1 = S[i + 1];
  float s = 0.0f;
  for (int e = e0 + lane; e < e1; e += 64) s += ewp[e];
  s = wave_sum64(s);
  if (lane == 0) dinv[i] = rsqrtf(s + 1.0f);
}

__global__ __launch_bounds__(256) void nrm_kernel(
    const int* __restrict__ S, const int* __restrict__ srcbuf,
    const float* __restrict__ ewp, const float* __restrict__ dinv,
    float* __restrict__ nrm) {
  int i = (int)(((size_t)blockIdx.x * blockDim.x + threadIdx.x) >> 6);
  int lane = threadIdx.x & 63;
  if (i >= NG) return;
  float di = dinv[i];
  int e0 = S[i], e1 = S[i + 1];
  for (int e = e0 + lane; e < e1; e += 64)
    nrm[e] = dinv[srcbuf[e]] * ewp[e] * di;
}

// ---------------- fused glom layer (scalar gather + readlane matmul) --------
__global__ __launch_bounds__(256) void glom_layer_kernel(
    const int* __restrict__ rp_gg, const int* __restrict__ rp_cg,
    const int* __restrict__ srcbuf, const float* __restrict__ nrm_gg,
    const __half* __restrict__ xg_old, const __half* __restrict__ xc_old,
    const float* __restrict__ dinv,
    const float* __restrict__ W_gcn, const float* __restrict__ b_gcn,
    const float* __restrict__ eps_cg, const float* __restrict__ W_cg,
    const float* __restrict__ b_cg,
    const float* __restrict__ ls, const float* __restrict__ lb,
    __half* __restrict__ xg_new, int n) {
  int i = (int)(((size_t)blockIdx.x * blockDim.x + threadIdx.x) >> 6);
  int lane = threadIdx.x & 63;
  if (i >= n) return;
  int iu = __builtin_amdgcn_readfirstlane(i);
  int ge0 = __builtin_amdgcn_readfirstlane(rp_gg[iu]);
  int ge1 = __builtin_amdgcn_readfirstlane(rp_gg[iu + 1]);
  int fe0 = __builtin_amdgcn_readfirstlane(rp_cg[iu]);
  int fe1 = __builtin_amdgcn_readfirstlane(rp_cg[iu + 1]);
  float self = __half2float(xg_old[(size_t)iu * D + lane]);
  float di = dinv[iu];
  float accG = di * di * self
             + csr_gather_s(srcbuf, nrm_gg, xg_old, ge0, ge1, lane);
  float accC = csr_gather_s(srcbuf, nullptr, xc_old, fe0, fe1, lane);
  float gcn = b_gcn[lane];
#pragma unroll
  for (int k = 0; k < 64; ++k)
    gcn = fmaf(bcast_lane(accG, k), W_gcn[k * 64 + lane], gcn);
  float h = (1.0f + eps_cg[0]) * self + accC;
  float gin = b_cg[lane];
#pragma unroll
  for (int k = 0; k < 64; ++k)
    gin = fmaf(bcast_lane(h, k), W_cg[k * 64 + lane], gin);
  float g = gcn + fmaxf(gin, 0.0f);
  float m = wave_sum64(g) * (1.0f / 64.0f);
  float d = g - m;
  float var = wave_sum64(d * d) * (1.0f / 64.0f);
  float o = d * rsqrtf(var + LN_EPS) * ls[lane] + lb[lane];
  xg_new[(size_t)iu * D + lane] = __float2half(fmaxf(o, 0.0f));
}

// ---------------- fused cell layer ------------------------------------------
__global__ __launch_bounds__(256) void cell_layer_kernel(
    const int* __restrict__ rp_cc, const int* __restrict__ srcbuf,
    const __half* __restrict__ xc_old,
    const float* __restrict__ eps_cc, const float* __restrict__ W_cc,
    const float* __restrict__ b_cc,
    const float* __restrict__ ls, const float* __restrict__ lb,
    __half* __restrict__ xc_new, int n) {
  int i = (int)(((size_t)blockIdx.x * blockDim.x + threadIdx.x) >> 6);
  int lane = threadIdx.x & 63;
  if (i >= n) return;
  int iu = __builtin_amdgcn_readfirstlane(i);
  int e0 = __builtin_amdgcn_readfirstlane(rp_cc[iu]);
  int e1 = __builtin_amdgcn_readfirstlane(rp_cc[iu + 1]);
  float self = __half2float(xc_old[(size_t)iu * D + lane]);
  float acc = csr_gather_s(srcbuf, nullptr, xc_old, e0, e1, lane);
  float h = (1.0f + eps_cc[0]) * self + acc;
  float gin = b_cc[lane];
#pragma unroll
  for (int k = 0; k < 64; ++k)
    gin = fmaf(bcast_lane(h, k), W_cc[k * 64 + lane], gin);
  float g = fmaxf(gin, 0.0f);
  float m = wave_sum64(g) * (1.0f / 64.0f);
  float d = g - m;
  float var = wave_sum64(d * d) * (1.0f / 64.0f);
  float o = d * rsqrtf(var + LN_EPS) * ls[lane] + lb[lane];
  xc_new[(size_t)iu * D + lane] = __float2half(fmaxf(o, 0.0f));
}

// ---------------- output head: wave per row --------------------------------
__global__ __launch_bounds__(256) void out_kernel(
    const __half* __restrict__ xg, const float* __restrict__ W,
    const float* __restrict__ b, float* __restrict__ out, int n) {
  int wid = (int)(((size_t)blockIdx.x * blockDim.x + threadIdx.x) >> 6);
  int lane = threadIdx.x & 63;
  if (wid >= n) return;
  float v = __half2float(xg[(size_t)wid * D + lane]);
  float a0 = wave_sum64(v * W[lane * 3 + 0]) + b[0];
  float a1 = wave_sum64(v * W[lane * 3 + 1]) + b[1];
  float a2 = wave_sum64(v * W[lane * 3 + 2]) + b[2];
  float m = fmaxf(a0, fmaxf(a1, a2));
  float e0 = expf(a0 - m), e1 = expf(a1 - m), e2 = expf(a2 - m);
  float inv = 1.0f / (e0 + e1 + e2);
  if (lane == 0) {
    out[(size_t)wid * 3 + 0] = e0 * inv;
    out[(size_t)wid * 3 + 1] = e1 * inv;
    out[(size_t)wid * 3 + 2] = e2 * inv;
  }
}

extern "C" void kernel_launch(void* const* d_in, const int* in_sizes, int n_in,
                              void* d_out, int out_size, void* d_ws, size_t ws_size,
                              hipStream_t stream) {
  const float* x_glom = (const float*)d_in[0];
  const float* x_cell = (const float*)d_in[1];
  const int*   ei_gg  = (const int*)d_in[2];
  const float* ew_gg  = (const float*)d_in[3];
  const int*   ei_cg  = (const int*)d_in[4];
  const int*   ei_cc  = (const int*)d_in[5];
  const float* W_in_g = (const float*)d_in[6];
  const float* b_in_g = (const float*)d_in[7];
  const float* lnig_s = (const float*)d_in[8];
  const float* lnig_b = (const float*)d_in[9];
  const float* W_in_c = (const float*)d_in[10];
  const float* b_in_c = (const float*)d_in[11];
  const float* lnic_s = (const float*)d_in[12];
  const float* lnic_b = (const float*)d_in[13];
  const float* W_outp = (const float*)d_in[34];
  const float* b_outp = (const float*)d_in[35];

  // ---- workspace layout ----
  char* P = (char*)d_ws;
  __half* xg0 = (__half*)P;                    P += (size_t)NG * D * 2;
  __half* xg1 = (__half*)P;                    P += (size_t)NG * D * 2;
  __half* xc0 = (__half*)P;                    P += (size_t)NC * D * 2;
  __half* xc1 = (__half*)P;                    P += (size_t)NC * D * 2;
  float* dinv = (float*)P;                     P += (size_t)NG * 4;
  float* nrm  = (float*)P;                     P += (size_t)EGG * 4;
  int* S      = (int*)P;                       P += (size_t)(SCAN_N + 1) * 4;
  int* srcbuf = (int*)P;                       P += (size_t)E_ALL * 4;
  int* bhist  = (int*)P;                       P += (size_t)NBKT * NBLK * 4;
  int* base   = (int*)P;                       P += (size_t)NBKT * NBLK * 4;
  int* btot   = (int*)P;                       P += (size_t)NBKT * 4;
  int* bbase  = (int*)P;                       P += (size_t)(NBKT + 1) * 4;
  // transients over the feature-table region (dead before fc_in writes it)
  int* ssort   = (int*)d_ws;
  float* wsort = (float*)(ssort + E_ALL);
  float* ewp   = wsort + EGG;

  dim3 blk(256);
  auto wgrid = [](long long waves) { return dim3((unsigned)((waves + 3) / 4)); };

  // ---- CSR build: atomic-free two-level counting sort ----
  hipMemsetAsync(btot, 0, NBKT * sizeof(int), stream);
  r1_hist_kernel<<<dim3(NBLK), blk, 0, stream>>>(ei_gg, ei_cg, ei_cc, bhist, btot);
  r2b_kernel<<<dim3(1), dim3(256), 0, stream>>>(btot, bbase, S);
  r2c_kernel<<<dim3(NBKT), dim3(512), 0, stream>>>(bhist, bbase, base);
  r3_scatter_kernel<<<dim3(NBLK), blk, 0, stream>>>(
      ei_gg, ew_gg, ei_cg, ei_cc, base, ssort, wsort);
  r4_sort_kernel<<<dim3(NBKT), dim3(1024), 0, stream>>>(
      ssort, wsort, bbase, S, srcbuf, ewp);
  deg_kernel<<<wgrid(NG), blk, 0, stream>>>(S, ewp, dinv);
  nrm_kernel<<<wgrid(NG), blk, 0, stream>>>(S, srcbuf, ewp, dinv, nrm);

  // ---- input FCs (overwrite the transient ssort/wsort/ewp region) ----
  fc_in_kernel<<<wgrid((NG + 3) / 4), blk, 0, stream>>>(
      x_glom, W_in_g, b_in_g, lnig_s, lnig_b, xg0, NG);
  fc_in_kernel<<<wgrid((NC + 3) / 4), blk, 0, stream>>>(
      x_cell, W_in_c, b_in_c, lnic_s, lnic_b, xc0, NC);

  // ---- two hetero MP layers (split kernels, double-buffered) ----
  const int* rp_gg = S;
  const int* rp_cg = S + NG;
  const int* rp_cc = S + 2 * NG;
  __half* xg_cur = xg0; __half* xg_nxt = xg1;
  __half* xc_cur = xc0; __half* xc_nxt = xc1;
  for (int l = 0; l < 2; ++l) {
    const float* const* p = (const float* const*)(d_in + 14 + 10 * l);
    const float* W_gcn = p[0]; const float* b_gcn = p[1];
    const float* eps_cg = p[2]; const float* W_cg = p[3]; const float* b_cg = p[4];
    const float* eps_cc = p[5]; const float* W_cc = p[6]; const float* b_cc = p[7];
    const float* ln_s = p[8]; const float* ln_b = p[9];

    glom_layer_kernel<<<wgrid(NG), blk, 0, stream>>>(
        rp_gg, rp_cg, srcbuf, nrm, xg_cur, xc_cur, dinv,
        W_gcn, b_gcn, eps_cg, W_cg, b_cg, ln_s, ln_b, xg_nxt, NG);
    cell_layer_kernel<<<wgrid(NC), blk, 0, stream>>>(
        rp_cc, srcbuf, xc_cur, eps_cc, W_cc, b_cc, ln_s, ln_b, xc_nxt, NC);

    __half* t;
    t = xg_cur; xg_cur = xg_nxt; xg_nxt = t;
    t = xc_cur; xc_cur = xc_nxt; xc_nxt = t;
  }

  out_kernel<<<wgrid(NG), blk, 0, stream>>>(xg_cur, W_outp, b_outp, (float*)d_out, NG);
}

// Round 13
// 503.537 us; speedup vs baseline: 1.8792x; 1.1780x over previous
//
#include <hip/hip_runtime.h>
#include <hip/hip_fp16.h>

#define NG 50000
#define NC 100000
#define DIN 128
#define D 64
#define EGG 800000
#define ECG 1600000
#define ECC 1600000
#define LN_EPS 1e-5f

#define SCAN_N (2 * NG + NC)            // 200000 keys: gg dst | cg dst | cc dst
#define E_ALL (EGG + ECG + ECC)         // 4,000,000 edges
#define NBKT 196                        // buckets of 1024 keys
#define NBLK 512                        // blocks in R1/R3
#define EPB ((E_ALL + NBLK - 1) / NBLK) // edges per block = 7813

typedef _Float16 f16x8 __attribute__((ext_vector_type(8)));
typedef float f32x4 __attribute__((ext_vector_type(4)));

__device__ __forceinline__ float wave_sum64(float v) {
#pragma unroll
  for (int off = 32; off > 0; off >>= 1) v += __shfl_xor(v, off);
  return v;
}

__device__ __forceinline__ float bcast_lane(float v, int k) {
  // compile-time k -> v_readlane_b32 (VALU), NOT ds_bpermute (DS pipe)
  return __int_as_float(__builtin_amdgcn_readlane(__float_as_int(v), k));
}

// ---- scalar-indexed fp16 CSR gather ----------------------------------------
// e0/e1 wave-uniform (SGPR). Index/weight loads go down the scalar pipe;
// row reads are 1 coalesced global_load_ushort per lane (lane = dim).
__device__ __forceinline__ float csr_gather_s(
    const int* __restrict__ src, const float* __restrict__ nrm,
    const __half* __restrict__ tab, int e0, int e1, int lane) {
  float a0 = 0.f, a1 = 0.f, a2 = 0.f, a3 = 0.f;
  int e = e0;
  for (; e + 8 <= e1; e += 8) {
    int s0 = src[e + 0], s1 = src[e + 1], s2 = src[e + 2], s3 = src[e + 3];
    int s4 = src[e + 4], s5 = src[e + 5], s6 = src[e + 6], s7 = src[e + 7];
    __half v0 = tab[(size_t)s0 * D + lane];
    __half v1 = tab[(size_t)s1 * D + lane];
    __half v2 = tab[(size_t)s2 * D + lane];
    __half v3 = tab[(size_t)s3 * D + lane];
    __half v4 = tab[(size_t)s4 * D + lane];
    __half v5 = tab[(size_t)s5 * D + lane];
    __half v6 = tab[(size_t)s6 * D + lane];
    __half v7 = tab[(size_t)s7 * D + lane];
    if (nrm) {
      a0 = fmaf(nrm[e + 0], __half2float(v0), a0);
      a1 = fmaf(nrm[e + 1], __half2float(v1), a1);
      a2 = fmaf(nrm[e + 2], __half2float(v2), a2);
      a3 = fmaf(nrm[e + 3], __half2float(v3), a3);
      a0 = fmaf(nrm[e + 4], __half2float(v4), a0);
      a1 = fmaf(nrm[e + 5], __half2float(v5), a1);
      a2 = fmaf(nrm[e + 6], __half2float(v6), a2);
      a3 = fmaf(nrm[e + 7], __half2float(v7), a3);
    } else {
      a0 += __half2float(v0); a1 += __half2float(v1);
      a2 += __half2float(v2); a3 += __half2float(v3);
      a0 += __half2float(v4); a1 += __half2float(v5);
      a2 += __half2float(v6); a3 += __half2float(v7);
    }
  }
  for (; e < e1; ++e) {
    int s = src[e];
    float v = __half2float(tab[(size_t)s * D + lane]);
    if (nrm) a0 = fmaf(nrm[e], v, a0); else a0 += v;
  }
  return (a0 + a1) + (a2 + a3);
}

// ---------------- dense input FC via MFMA -----------------------------------
// One wave per 16-row tile: C16x16 = A16x32 * B32x16, 4 k-steps x 4 n-tiles.
// A frag: row = lane&15, k = k0 + (lane>>4)*8 + j   (8 contiguous k / lane)
// B frag: col = lane&15, k = k0 + (lane>>4)*8 + j
// C frag (verified): col = lane&15, row = (lane>>4)*4 + reg
// LN per row = 4-stage shfl_xor within each 16-lane group.
__global__ __launch_bounds__(256) void fc_in_mfma_kernel(
    const float* __restrict__ x, const float* __restrict__ W,
    const float* __restrict__ b, const float* __restrict__ s,
    const float* __restrict__ beta, __half* __restrict__ y, int n) {
  int wid = (int)(((size_t)blockIdx.x * blockDim.x + threadIdx.x) >> 6);
  int lane = threadIdx.x & 63;
  int r0 = wid * 16;
  if (r0 >= n) return;          // n % 16 == 0 for both node types
  int lo = lane & 15;
  int hi = lane >> 4;

  // hoist B fragments (W is L1-hot): 16 frags = 64 VGPRs
  f16x8 bf[4][4];
#pragma unroll
  for (int kk = 0; kk < 4; ++kk) {
    int kbase = kk * 32 + hi * 8;
#pragma unroll
    for (int t = 0; t < 4; ++t) {
      int c = t * 16 + lo;
      f16x8 v;
#pragma unroll
      for (int j = 0; j < 8; ++j)
        v[j] = (_Float16)W[(kbase + j) * 64 + c];
      bf[kk][t] = v;
    }
  }

  f32x4 acc[4];
#pragma unroll
  for (int t = 0; t < 4; ++t) acc[t] = (f32x4){0.f, 0.f, 0.f, 0.f};

  const float* xr = x + (size_t)(r0 + lo) * DIN;
#pragma unroll
  for (int kk = 0; kk < 4; ++kk) {
    int kbase = kk * 32 + hi * 8;
    float4 xa = *(const float4*)(xr + kbase);
    float4 xb = *(const float4*)(xr + kbase + 4);
    f16x8 af;
    af[0] = (_Float16)xa.x; af[1] = (_Float16)xa.y;
    af[2] = (_Float16)xa.z; af[3] = (_Float16)xa.w;
    af[4] = (_Float16)xb.x; af[5] = (_Float16)xb.y;
    af[6] = (_Float16)xb.z; af[7] = (_Float16)xb.w;
#pragma unroll
    for (int t = 0; t < 4; ++t)
      acc[t] = __builtin_amdgcn_mfma_f32_16x16x32_f16(af, bf[kk][t], acc[t], 0, 0, 0);
  }

  // bias + LN + relu + store
  float bc[4], lsv[4], lbv[4];
#pragma unroll
  for (int t = 0; t < 4; ++t) {
    int c = t * 16 + lo;
    bc[t] = b[c]; lsv[t] = s[c]; lbv[t] = beta[c];
  }
#pragma unroll
  for (int reg = 0; reg < 4; ++reg) {
    float v[4];
    float s1 = 0.0f;
#pragma unroll
    for (int t = 0; t < 4; ++t) { v[t] = acc[t][reg] + bc[t]; s1 += v[t]; }
#pragma unroll
    for (int off = 1; off < 16; off <<= 1) s1 += __shfl_xor(s1, off);
    float m = s1 * (1.0f / 64.0f);
    float s2 = 0.0f;
#pragma unroll
    for (int t = 0; t < 4; ++t) { float d = v[t] - m; s2 += d * d; }
#pragma unroll
    for (int off = 1; off < 16; off <<= 1) s2 += __shfl_xor(s2, off);
    float rinv = rsqrtf(s2 * (1.0f / 64.0f) + LN_EPS);
    int r = r0 + hi * 4 + reg;
#pragma unroll
    for (int t = 0; t < 4; ++t) {
      float o = (v[t] - m) * rinv * lsv[t] + lbv[t];
      y[(size_t)r * D + t * 16 + lo] = __float2half(fmaxf(o, 0.0f));
    }
  }
}

// =============== atomic-free CSR build: 2-level counting sort ===============
__global__ __launch_bounds__(256) void r1_hist_kernel(
    const int* __restrict__ ei_gg, const int* __restrict__ ei_cg,
    const int* __restrict__ ei_cc, int* __restrict__ bhist,
    int* __restrict__ btot) {
  __shared__ int hist[256];
  int t = threadIdx.x;
  int k = blockIdx.x;
  hist[t] = 0;
  __syncthreads();
  int base = k * EPB;
  for (int i = t; i < EPB; i += 256) {
    int e = base + i;
    if (e >= E_ALL) break;
    int key;
    if (e < EGG) key = ei_gg[EGG + e];
    else if (e < EGG + ECG) key = NG + ei_cg[ECG + (e - EGG)];
    else key = 2 * NG + ei_cc[ECC + (e - EGG - ECG)];
    atomicAdd(&hist[key >> 10], 1);
  }
  __syncthreads();
  if (t < NBKT) {
    bhist[t * NBLK + k] = hist[t];
    atomicAdd(&btot[t], hist[t]);
  }
}

__global__ __launch_bounds__(256) void r2b_kernel(
    const int* __restrict__ btot, int* __restrict__ bbase,
    int* __restrict__ S) {
  __shared__ int sh[256];
  int t = threadIdx.x;
  int v = (t < NBKT) ? btot[t] : 0;
  sh[t] = v;
  __syncthreads();
#pragma unroll
  for (int off = 1; off < 256; off <<= 1) {
    int u = (t >= off) ? sh[t - off] : 0;
    __syncthreads();
    sh[t] += u;
    __syncthreads();
  }
  if (t < NBKT) bbase[t] = sh[t] - v;
  if (t == 255) { bbase[NBKT] = sh[255]; S[SCAN_N] = sh[255]; }
}

__global__ __launch_bounds__(512) void r2c_kernel(
    const int* __restrict__ bhist, const int* __restrict__ bbase,
    int* __restrict__ base) {
  int b = blockIdx.x;
  int t = threadIdx.x;
  int lane = t & 63, wv = t >> 6;
  int v = bhist[b * NBLK + t];
  int sc = v;
#pragma unroll
  for (int off = 1; off < 64; off <<= 1) {
    int u = __shfl_up(sc, off);
    if (lane >= off) sc += u;
  }
  __shared__ int ws[8];
  if (lane == 63) ws[wv] = sc;
  __syncthreads();
  int wb = 0;
  for (int i = 0; i < wv; ++i) wb += ws[i];
  base[b * NBLK + t] = bbase[b] + wb + sc - v;
}

__global__ __launch_bounds__(256) void r3_scatter_kernel(
    const int* __restrict__ ei_gg, const float* __restrict__ ew_gg,
    const int* __restrict__ ei_cg, const int* __restrict__ ei_cc,
    const int* __restrict__ base, int* __restrict__ ssort,
    float* __restrict__ wsort) {
  __shared__ int cur[256];
  int t = threadIdx.x;
  int k = blockIdx.x;
  if (t < NBKT) cur[t] = base[t * NBLK + k];
  __syncthreads();
  int bb = k * EPB;
  for (int i = t; i < EPB; i += 256) {
    int e = bb + i;
    if (e >= E_ALL) break;
    int key, s; float w = 0.0f; bool isg = false;
    if (e < EGG) {
      key = ei_gg[EGG + e]; s = ei_gg[e]; w = ew_gg[e]; isg = true;
    } else if (e < EGG + ECG) {
      int q = e - EGG; key = NG + ei_cg[ECG + q]; s = ei_cg[q];
    } else {
      int q = e - EGG - ECG; key = 2 * NG + ei_cc[ECC + q]; s = ei_cc[q];
    }
    int p = atomicAdd(&cur[key >> 10], 1);   // LDS atomic
    ssort[p] = ((key & 1023) << 17) | s;     // src < 2^17
    if (isg) wsort[p] = w;
  }
}

__global__ __launch_bounds__(1024) void r4_sort_kernel(
    const int* __restrict__ ssort, const float* __restrict__ wsort,
    const int* __restrict__ bbase, int* __restrict__ S,
    int* __restrict__ srcbuf, float* __restrict__ ewp) {
  int b = blockIdx.x;
  int t = threadIdx.x;
  int e0 = bbase[b], e1 = bbase[b + 1];
  int kbase = b << 10;
  __shared__ int hist[1024];
  __shared__ int sh[1024];
  __shared__ int cur[1024];
  hist[t] = 0;
  __syncthreads();
  for (int e = e0 + t; e < e1; e += 1024)
    atomicAdd(&hist[((unsigned)ssort[e]) >> 17], 1);
  __syncthreads();
  int c = hist[t];
  sh[t] = c;
  __syncthreads();
#pragma unroll
  for (int off = 1; off < 1024; off <<= 1) {
    int u = (t >= off) ? sh[t - off] : 0;
    __syncthreads();
    sh[t] += u;
    __syncthreads();
  }
  int ex = e0 + sh[t] - c;
  int key = kbase + t;
  if (key < SCAN_N) S[key] = ex;
  cur[t] = ex;
  __syncthreads();
  for (int e = e0 + t; e < e1; e += 1024) {
    int rec = ssort[e];
    int lk = ((unsigned)rec) >> 17;
    int p = atomicAdd(&cur[lk], 1);
    srcbuf[p] = rec & 0x1FFFF;
    if (kbase + lk < NG) ewp[p] = wsort[e];
  }
}

__global__ __launch_bounds__(256) void deg_kernel(
    const int* __restrict__ S, const float* __restrict__ ewp,
    float* __restrict__ dinv) {
  int i = (int)(((size_t)blockIdx.x * blockDim.x + threadIdx.x) >> 6);
  int lane = threadIdx.x & 63;
  if (i >= NG) return;
  int e0 = S[i], e1 = S[i + 1];
  float s = 0.0f;
  for (int e = e0 + lane; e < e1; e += 64) s += ewp[e];
  s = wave_sum64(s);
  if (lane == 0) dinv[i] = rsqrtf(s + 1.0f);
}

__global__ __launch_bounds__(256) void nrm_kernel(
    const int* __restrict__ S, const int* __restrict__ srcbuf,
    const float* __restrict__ ewp, const float* __restrict__ dinv,
    float* __restrict__ nrm) {
  int i = (int)(((size_t)blockIdx.x * blockDim.x + threadIdx.x) >> 6);
  int lane = threadIdx.x & 63;
  if (i >= NG) return;
  float di = dinv[i];
  int e0 = S[i], e1 = S[i + 1];
  for (int e = e0 + lane; e < e1; e += 64)
    nrm[e] = dinv[srcbuf[e]] * ewp[e] * di;
}

// ---------------- fused glom layer (scalar gather + readlane matmul) --------
__global__ __launch_bounds__(256) void glom_layer_kernel(
    const int* __restrict__ rp_gg, const int* __restrict__ rp_cg,
    const int* __restrict__ srcbuf, const float* __restrict__ nrm_gg,
    const __half* __restrict__ xg_old, const __half* __restrict__ xc_old,
    const float* __restrict__ dinv,
    const float* __restrict__ W_gcn, const float* __restrict__ b_gcn,
    const float* __restrict__ eps_cg, const float* __restrict__ W_cg,
    const float* __restrict__ b_cg,
    const float* __restrict__ ls, const float* __restrict__ lb,
    __half* __restrict__ xg_new, int n) {
  int i = (int)(((size_t)blockIdx.x * blockDim.x + threadIdx.x) >> 6);
  int lane = threadIdx.x & 63;
  if (i >= n) return;
  int iu = __builtin_amdgcn_readfirstlane(i);
  int ge0 = __builtin_amdgcn_readfirstlane(rp_gg[iu]);
  int ge1 = __builtin_amdgcn_readfirstlane(rp_gg[iu + 1]);
  int fe0 = __builtin_amdgcn_readfirstlane(rp_cg[iu]);
  int fe1 = __builtin_amdgcn_readfirstlane(rp_cg[iu + 1]);
  float self = __half2float(xg_old[(size_t)iu * D + lane]);
  float di = dinv[iu];
  float accG = di * di * self
             + csr_gather_s(srcbuf, nrm_gg, xg_old, ge0, ge1, lane);
  float accC = csr_gather_s(srcbuf, nullptr, xc_old, fe0, fe1, lane);
  float gcn = b_gcn[lane];
#pragma unroll
  for (int k = 0; k < 64; ++k)
    gcn = fmaf(bcast_lane(accG, k), W_gcn[k * 64 + lane], gcn);
  float h = (1.0f + eps_cg[0]) * self + accC;
  float gin = b_cg[lane];
#pragma unroll
  for (int k = 0; k < 64; ++k)
    gin = fmaf(bcast_lane(h, k), W_cg[k * 64 + lane], gin);
  float g = gcn + fmaxf(gin, 0.0f);
  float m = wave_sum64(g) * (1.0f / 64.0f);
  float d = g - m;
  float var = wave_sum64(d * d) * (1.0f / 64.0f);
  float o = d * rsqrtf(var + LN_EPS) * ls[lane] + lb[lane];
  xg_new[(size_t)iu * D + lane] = __float2half(fmaxf(o, 0.0f));
}

// ---------------- fused cell layer ------------------------------------------
__global__ __launch_bounds__(256) void cell_layer_kernel(
    const int* __restrict__ rp_cc, const int* __restrict__ srcbuf,
    const __half* __restrict__ xc_old,
    const float* __restrict__ eps_cc, const float* __restrict__ W_cc,
    const float* __restrict__ b_cc,
    const float* __restrict__ ls, const float* __restrict__ lb,
    __half* __restrict__ xc_new, int n) {
  int i = (int)(((size_t)blockIdx.x * blockDim.x + threadIdx.x) >> 6);
  int lane = threadIdx.x & 63;
  if (i >= n) return;
  int iu = __builtin_amdgcn_readfirstlane(i);
  int e0 = __builtin_amdgcn_readfirstlane(rp_cc[iu]);
  int e1 = __builtin_amdgcn_readfirstlane(rp_cc[iu + 1]);
  float self = __half2float(xc_old[(size_t)iu * D + lane]);
  float acc = csr_gather_s(srcbuf, nullptr, xc_old, e0, e1, lane);
  float h = (1.0f + eps_cc[0]) * self + acc;
  float gin = b_cc[lane];
#pragma unroll
  for (int k = 0; k < 64; ++k)
    gin = fmaf(bcast_lane(h, k), W_cc[k * 64 + lane], gin);
  float g = fmaxf(gin, 0.0f);
  float m = wave_sum64(g) * (1.0f / 64.0f);
  float d = g - m;
  float var = wave_sum64(d * d) * (1.0f / 64.0f);
  float o = d * rsqrtf(var + LN_EPS) * ls[lane] + lb[lane];
  xc_new[(size_t)iu * D + lane] = __float2half(fmaxf(o, 0.0f));
}

// ---------------- output head: wave per row --------------------------------
__global__ __launch_bounds__(256) void out_kernel(
    const __half* __restrict__ xg, const float* __restrict__ W,
    const float* __restrict__ b, float* __restrict__ out, int n) {
  int wid = (int)(((size_t)blockIdx.x * blockDim.x + threadIdx.x) >> 6);
  int lane = threadIdx.x & 63;
  if (wid >= n) return;
  float v = __half2float(xg[(size_t)wid * D + lane]);
  float a0 = wave_sum64(v * W[lane * 3 + 0]) + b[0];
  float a1 = wave_sum64(v * W[lane * 3 + 1]) + b[1];
  float a2 = wave_sum64(v * W[lane * 3 + 2]) + b[2];
  float m = fmaxf(a0, fmaxf(a1, a2));
  float e0 = expf(a0 - m), e1 = expf(a1 - m), e2 = expf(a2 - m);
  float inv = 1.0f / (e0 + e1 + e2);
  if (lane == 0) {
    out[(size_t)wid * 3 + 0] = e0 * inv;
    out[(size_t)wid * 3 + 1] = e1 * inv;
    out[(size_t)wid * 3 + 2] = e2 * inv;
  }
}

extern "C" void kernel_launch(void* const* d_in, const int* in_sizes, int n_in,
                              void* d_out, int out_size, void* d_ws, size_t ws_size,
                              hipStream_t stream) {
  const float* x_glom = (const float*)d_in[0];
  const float* x_cell = (const float*)d_in[1];
  const int*   ei_gg  = (const int*)d_in[2];
  const float* ew_gg  = (const float*)d_in[3];
  const int*   ei_cg  = (const int*)d_in[4];
  const int*   ei_cc  = (const int*)d_in[5];
  const float* W_in_g = (const float*)d_in[6];
  const float* b_in_g = (const float*)d_in[7];
  const float* lnig_s = (const float*)d_in[8];
  const float* lnig_b = (const float*)d_in[9];
  const float* W_in_c = (const float*)d_in[10];
  const float* b_in_c = (const float*)d_in[11];
  const float* lnic_s = (const float*)d_in[12];
  const float* lnic_b = (const float*)d_in[13];
  const float* W_outp = (const float*)d_in[34];
  const float* b_outp = (const float*)d_in[35];

  // ---- workspace layout ----
  char* P = (char*)d_ws;
  __half* xg0 = (__half*)P;                    P += (size_t)NG * D * 2;
  __half* xg1 = (__half*)P;                    P += (size_t)NG * D * 2;
  __half* xc0 = (__half*)P;                    P += (size_t)NC * D * 2;
  __half* xc1 = (__half*)P;                    P += (size_t)NC * D * 2;
  float* dinv = (float*)P;                     P += (size_t)NG * 4;
  float* nrm  = (float*)P;                     P += (size_t)EGG * 4;
  int* S      = (int*)P;                       P += (size_t)(SCAN_N + 1) * 4;
  int* srcbuf = (int*)P;                       P += (size_t)E_ALL * 4;
  int* bhist  = (int*)P;                       P += (size_t)NBKT * NBLK * 4;
  int* base   = (int*)P;                       P += (size_t)NBKT * NBLK * 4;
  int* btot   = (int*)P;                       P += (size_t)NBKT * 4;
  int* bbase  = (int*)P;                       P += (size_t)(NBKT + 1) * 4;
  // transients over the feature-table region (dead before fc_in writes it)
  int* ssort   = (int*)d_ws;
  float* wsort = (float*)(ssort + E_ALL);
  float* ewp   = wsort + EGG;

  dim3 blk(256);
  auto wgrid = [](long long waves) { return dim3((unsigned)((waves + 3) / 4)); };

  // ---- CSR build: atomic-free two-level counting sort ----
  hipMemsetAsync(btot, 0, NBKT * sizeof(int), stream);
  r1_hist_kernel<<<dim3(NBLK), blk, 0, stream>>>(ei_gg, ei_cg, ei_cc, bhist, btot);
  r2b_kernel<<<dim3(1), dim3(256), 0, stream>>>(btot, bbase, S);
  r2c_kernel<<<dim3(NBKT), dim3(512), 0, stream>>>(bhist, bbase, base);
  r3_scatter_kernel<<<dim3(NBLK), blk, 0, stream>>>(
      ei_gg, ew_gg, ei_cg, ei_cc, base, ssort, wsort);
  r4_sort_kernel<<<dim3(NBKT), dim3(1024), 0, stream>>>(
      ssort, wsort, bbase, S, srcbuf, ewp);
  deg_kernel<<<wgrid(NG), blk, 0, stream>>>(S, ewp, dinv);
  nrm_kernel<<<wgrid(NG), blk, 0, stream>>>(S, srcbuf, ewp, dinv, nrm);

  // ---- input FCs via MFMA (overwrite the transient ssort/wsort/ewp region) --
  fc_in_mfma_kernel<<<wgrid(NG / 16), blk, 0, stream>>>(
      x_glom, W_in_g, b_in_g, lnig_s, lnig_b, xg0, NG);
  fc_in_mfma_kernel<<<wgrid(NC / 16), blk, 0, stream>>>(
      x_cell, W_in_c, b_in_c, lnic_s, lnic_b, xc0, NC);

  // ---- two hetero MP layers (split kernels, double-buffered) ----
  const int* rp_gg = S;
  const int* rp_cg = S + NG;
  const int* rp_cc = S + 2 * NG;
  __half* xg_cur = xg0; __half* xg_nxt = xg1;
  __half* xc_cur = xc0; __half* xc_nxt = xc1;
  for (int l = 0; l < 2; ++l) {
    const float* const* p = (const float* const*)(d_in + 14 + 10 * l);
    const float* W_gcn = p[0]; const float* b_gcn = p[1];
    const float* eps_cg = p[2]; const float* W_cg = p[3]; const float* b_cg = p[4];
    const float* eps_cc = p[5]; const float* W_cc = p[6]; const float* b_cc = p[7];
    const float* ln_s = p[8]; const float* ln_b = p[9];

    glom_layer_kernel<<<wgrid(NG), blk, 0, stream>>>(
        rp_gg, rp_cg, srcbuf, nrm, xg_cur, xc_cur, dinv,
        W_gcn, b_gcn, eps_cg, W_cg, b_cg, ln_s, ln_b, xg_nxt, NG);
    cell_layer_kernel<<<wgrid(NC), blk, 0, stream>>>(
        rp_cc, srcbuf, xc_cur, eps_cc, W_cc, b_cc, ln_s, ln_b, xc_nxt, NC);

    __half* t;
    t = xg_cur; xg_cur = xg_nxt; xg_nxt = t;
    t = xc_cur; xc_cur = xc_nxt; xc_nxt = t;
  }

  out_kernel<<<wgrid(NG), blk, 0, stream>>>(xg_cur, W_outp, b_outp, (float*)d_out, NG);
}

// Round 14
// 474.186 us; speedup vs baseline: 1.9955x; 1.0619x over previous
//
#include <hip/hip_runtime.h>
#include <hip/hip_fp16.h>

#define NG 50000
#define NC 100000
#define DIN 128
#define D 64
#define EGG 800000
#define ECG 1600000
#define ECC 1600000
#define LN_EPS 1e-5f

#define SCAN_N (2 * NG + NC)            // 200000 keys: gg dst | cg dst | cc dst
#define E_ALL (EGG + ECG + ECC)         // 4,000,000 edges
#define NBKT 196                        // buckets of 1024 keys
#define NBLK 512                        // blocks in R1/R3
#define EPB ((E_ALL + NBLK - 1) / NBLK) // edges per block = 7813

typedef _Float16 f16x8 __attribute__((ext_vector_type(8)));
typedef float f32x4 __attribute__((ext_vector_type(4)));

__device__ __forceinline__ float wave_sum64(float v) {
#pragma unroll
  for (int off = 32; off > 0; off >>= 1) v += __shfl_xor(v, off);
  return v;
}

__device__ __forceinline__ float bcast_lane(float v, int k) {
  // compile-time k -> v_readlane_b32 (VALU), NOT ds_bpermute (DS pipe)
  return __int_as_float(__builtin_amdgcn_readlane(__float_as_int(v), k));
}

// ---- pair-edge scalar-indexed fp16 CSR gather -------------------------------
// e0/e1 wave-uniform (SGPR). lane = h*32+m: h = edge parity, m = dim pair.
// One half2 load covers 2 dims of 1 of 2 edges -> 8-deep unroll keeps 16 rows
// in flight per wave (2x the lane=dim version). Indices/weights are scalar
// loads (uniform) + one v_cndmask per pair to select by h. Tail masked by w=0
// with index clamp (reads past segment end stay inside srcbuf+pad).
__device__ __forceinline__ float csr_gather_s2(
    const int* __restrict__ src, const float* __restrict__ nrm,
    const __half* __restrict__ tab, int e0, int e1, int lane) {
  int h = lane >> 5;
  int m = lane & 31;
  float ax0 = 0.f, ax1 = 0.f, ax2 = 0.f, ax3 = 0.f;
  float ay0 = 0.f, ay1 = 0.f, ay2 = 0.f, ay3 = 0.f;
  for (int e = e0; e < e1; e += 16) {
#pragma unroll
    for (int p = 0; p < 8; ++p) {
      int i0 = e + 2 * p;
      int se = src[i0];          // SGPR (sequential s_load)
      int so = src[i0 + 1];      // SGPR
      int s = h ? so : se;       // v_cndmask
      bool valid = (i0 + h) < e1;
      float w;
      if (nrm) {
        float we = nrm[i0], wo = nrm[i0 + 1];
        w = h ? wo : we;
      } else {
        w = 1.0f;
      }
      w = valid ? w : 0.0f;
      s = valid ? s : 0;         // clamp: garbage index past segment is unsafe
      __half2 v = *(const __half2*)(tab + (size_t)s * D + 2 * m);
      float vl = __low2float(v), vh = __high2float(v);
      switch (p & 3) {
        case 0: ax0 = fmaf(w, vl, ax0); ay0 = fmaf(w, vh, ay0); break;
        case 1: ax1 = fmaf(w, vl, ax1); ay1 = fmaf(w, vh, ay1); break;
        case 2: ax2 = fmaf(w, vl, ax2); ay2 = fmaf(w, vh, ay2); break;
        default: ax3 = fmaf(w, vl, ax3); ay3 = fmaf(w, vh, ay3); break;
      }
    }
  }
  float ax = (ax0 + ax1) + (ax2 + ax3);
  float ay = (ay0 + ay1) + (ay2 + ay3);
  ax += __shfl_xor(ax, 32);   // combine even/odd edge halves
  ay += __shfl_xor(ay, 32);
  // redistribute pair layout -> lane=dim
  float ev = __shfl(ax, lane >> 1);
  float od = __shfl(ay, lane >> 1);
  return (lane & 1) ? od : ev;
}

// ---------------- dense input FC via MFMA -----------------------------------
__global__ __launch_bounds__(256) void fc_in_mfma_kernel(
    const float* __restrict__ x, const float* __restrict__ W,
    const float* __restrict__ b, const float* __restrict__ s,
    const float* __restrict__ beta, __half* __restrict__ y, int n) {
  int wid = (int)(((size_t)blockIdx.x * blockDim.x + threadIdx.x) >> 6);
  int lane = threadIdx.x & 63;
  int r0 = wid * 16;
  if (r0 >= n) return;          // n % 16 == 0 for both node types
  int lo = lane & 15;
  int hi = lane >> 4;

  f16x8 bf[4][4];
#pragma unroll
  for (int kk = 0; kk < 4; ++kk) {
    int kbase = kk * 32 + hi * 8;
#pragma unroll
    for (int t = 0; t < 4; ++t) {
      int c = t * 16 + lo;
      f16x8 v;
#pragma unroll
      for (int j = 0; j < 8; ++j)
        v[j] = (_Float16)W[(kbase + j) * 64 + c];
      bf[kk][t] = v;
    }
  }

  f32x4 acc[4];
#pragma unroll
  for (int t = 0; t < 4; ++t) acc[t] = (f32x4){0.f, 0.f, 0.f, 0.f};

  const float* xr = x + (size_t)(r0 + lo) * DIN;
#pragma unroll
  for (int kk = 0; kk < 4; ++kk) {
    int kbase = kk * 32 + hi * 8;
    float4 xa = *(const float4*)(xr + kbase);
    float4 xb = *(const float4*)(xr + kbase + 4);
    f16x8 af;
    af[0] = (_Float16)xa.x; af[1] = (_Float16)xa.y;
    af[2] = (_Float16)xa.z; af[3] = (_Float16)xa.w;
    af[4] = (_Float16)xb.x; af[5] = (_Float16)xb.y;
    af[6] = (_Float16)xb.z; af[7] = (_Float16)xb.w;
#pragma unroll
    for (int t = 0; t < 4; ++t)
      acc[t] = __builtin_amdgcn_mfma_f32_16x16x32_f16(af, bf[kk][t], acc[t], 0, 0, 0);
  }

  float bc[4], lsv[4], lbv[4];
#pragma unroll
  for (int t = 0; t < 4; ++t) {
    int c = t * 16 + lo;
    bc[t] = b[c]; lsv[t] = s[c]; lbv[t] = beta[c];
  }
#pragma unroll
  for (int reg = 0; reg < 4; ++reg) {
    float v[4];
    float s1 = 0.0f;
#pragma unroll
    for (int t = 0; t < 4; ++t) { v[t] = acc[t][reg] + bc[t]; s1 += v[t]; }
#pragma unroll
    for (int off = 1; off < 16; off <<= 1) s1 += __shfl_xor(s1, off);
    float m = s1 * (1.0f / 64.0f);
    float s2 = 0.0f;
#pragma unroll
    for (int t = 0; t < 4; ++t) { float d = v[t] - m; s2 += d * d; }
#pragma unroll
    for (int off = 1; off < 16; off <<= 1) s2 += __shfl_xor(s2, off);
    float rinv = rsqrtf(s2 * (1.0f / 64.0f) + LN_EPS);
    int r = r0 + hi * 4 + reg;
#pragma unroll
    for (int t = 0; t < 4; ++t) {
      float o = (v[t] - m) * rinv * lsv[t] + lbv[t];
      y[(size_t)r * D + t * 16 + lo] = __float2half(fmaxf(o, 0.0f));
    }
  }
}

// =============== atomic-free CSR build: 2-level counting sort ===============
__global__ __launch_bounds__(256) void r1_hist_kernel(
    const int* __restrict__ ei_gg, const int* __restrict__ ei_cg,
    const int* __restrict__ ei_cc, int* __restrict__ bhist,
    int* __restrict__ btot) {
  __shared__ int hist[256];
  int t = threadIdx.x;
  int k = blockIdx.x;
  hist[t] = 0;
  __syncthreads();
  int base = k * EPB;
  for (int i = t; i < EPB; i += 256) {
    int e = base + i;
    if (e >= E_ALL) break;
    int key;
    if (e < EGG) key = ei_gg[EGG + e];
    else if (e < EGG + ECG) key = NG + ei_cg[ECG + (e - EGG)];
    else key = 2 * NG + ei_cc[ECC + (e - EGG - ECG)];
    atomicAdd(&hist[key >> 10], 1);
  }
  __syncthreads();
  if (t < NBKT) {
    bhist[t * NBLK + k] = hist[t];
    atomicAdd(&btot[t], hist[t]);
  }
}

__global__ __launch_bounds__(256) void r2b_kernel(
    const int* __restrict__ btot, int* __restrict__ bbase,
    int* __restrict__ S) {
  __shared__ int sh[256];
  int t = threadIdx.x;
  int v = (t < NBKT) ? btot[t] : 0;
  sh[t] = v;
  __syncthreads();
#pragma unroll
  for (int off = 1; off < 256; off <<= 1) {
    int u = (t >= off) ? sh[t - off] : 0;
    __syncthreads();
    sh[t] += u;
    __syncthreads();
  }
  if (t < NBKT) bbase[t] = sh[t] - v;
  if (t == 255) { bbase[NBKT] = sh[255]; S[SCAN_N] = sh[255]; }
}

__global__ __launch_bounds__(512) void r2c_kernel(
    const int* __restrict__ bhist, const int* __restrict__ bbase,
    int* __restrict__ base) {
  int b = blockIdx.x;
  int t = threadIdx.x;
  int lane = t & 63, wv = t >> 6;
  int v = bhist[b * NBLK + t];
  int sc = v;
#pragma unroll
  for (int off = 1; off < 64; off <<= 1) {
    int u = __shfl_up(sc, off);
    if (lane >= off) sc += u;
  }
  __shared__ int ws[8];
  if (lane == 63) ws[wv] = sc;
  __syncthreads();
  int wb = 0;
  for (int i = 0; i < wv; ++i) wb += ws[i];
  base[b * NBLK + t] = bbase[b] + wb + sc - v;
}

__global__ __launch_bounds__(256) void r3_scatter_kernel(
    const int* __restrict__ ei_gg, const float* __restrict__ ew_gg,
    const int* __restrict__ ei_cg, const int* __restrict__ ei_cc,
    const int* __restrict__ base, int* __restrict__ ssort,
    float* __restrict__ wsort) {
  __shared__ int cur[256];
  int t = threadIdx.x;
  int k = blockIdx.x;
  if (t < NBKT) cur[t] = base[t * NBLK + k];
  __syncthreads();
  int bb = k * EPB;
  for (int i = t; i < EPB; i += 256) {
    int e = bb + i;
    if (e >= E_ALL) break;
    int key, s; float w = 0.0f; bool isg = false;
    if (e < EGG) {
      key = ei_gg[EGG + e]; s = ei_gg[e]; w = ew_gg[e]; isg = true;
    } else if (e < EGG + ECG) {
      int q = e - EGG; key = NG + ei_cg[ECG + q]; s = ei_cg[q];
    } else {
      int q = e - EGG - ECG; key = 2 * NG + ei_cc[ECC + q]; s = ei_cc[q];
    }
    int p = atomicAdd(&cur[key >> 10], 1);   // LDS atomic
    ssort[p] = ((key & 1023) << 17) | s;     // src < 2^17
    if (isg) wsort[p] = w;
  }
}

__global__ __launch_bounds__(1024) void r4_sort_kernel(
    const int* __restrict__ ssort, const float* __restrict__ wsort,
    const int* __restrict__ bbase, int* __restrict__ S,
    int* __restrict__ srcbuf, float* __restrict__ ewp) {
  int b = blockIdx.x;
  int t = threadIdx.x;
  int e0 = bbase[b], e1 = bbase[b + 1];
  int kbase = b << 10;
  __shared__ int hist[1024];
  __shared__ int sh[1024];
  __shared__ int cur[1024];
  hist[t] = 0;
  __syncthreads();
  for (int e = e0 + t; e < e1; e += 1024)
    atomicAdd(&hist[((unsigned)ssort[e]) >> 17], 1);
  __syncthreads();
  int c = hist[t];
  sh[t] = c;
  __syncthreads();
#pragma unroll
  for (int off = 1; off < 1024; off <<= 1) {
    int u = (t >= off) ? sh[t - off] : 0;
    __syncthreads();
    sh[t] += u;
    __syncthreads();
  }
  int ex = e0 + sh[t] - c;
  int key = kbase + t;
  if (key < SCAN_N) S[key] = ex;
  cur[t] = ex;
  __syncthreads();
  for (int e = e0 + t; e < e1; e += 1024) {
    int rec = ssort[e];
    int lk = ((unsigned)rec) >> 17;
    int p = atomicAdd(&cur[lk], 1);
    srcbuf[p] = rec & 0x1FFFF;
    if (kbase + lk < NG) ewp[p] = wsort[e];
  }
}

__global__ __launch_bounds__(256) void deg_kernel(
    const int* __restrict__ S, const float* __restrict__ ewp,
    float* __restrict__ dinv) {
  int i = (int)(((size_t)blockIdx.x * blockDim.x + threadIdx.x) >> 6);
  int lane = threadIdx.x & 63;
  if (i >= NG) return;
  int e0 = S[i], e1 = S[i + 1];
  float s = 0.0f;
  for (int e = e0 + lane; e < e1; e += 64) s += ewp[e];
  s = wave_sum64(s);
  if (lane == 0) dinv[i] = rsqrtf(s + 1.0f);
}

__global__ __launch_bounds__(256) void nrm_kernel(
    const int* __restrict__ S, const int* __restrict__ srcbuf,
    const float* __restrict__ ewp, const float* __restrict__ dinv,
    float* __restrict__ nrm) {
  int i = (int)(((size_t)blockIdx.x * blockDim.x + threadIdx.x) >> 6);
  int lane = threadIdx.x & 63;
  if (i >= NG) return;
  float di = dinv[i];
  int e0 = S[i], e1 = S[i + 1];
  for (int e = e0 + lane; e < e1; e += 64)
    nrm[e] = dinv[srcbuf[e]] * ewp[e] * di;
}

// ---------------- fused glom layer (pair-edge scalar gather) ----------------
__global__ __launch_bounds__(256) void glom_layer_kernel(
    const int* __restrict__ rp_gg, const int* __restrict__ rp_cg,
    const int* __restrict__ srcbuf, const float* __restrict__ nrm_gg,
    const __half* __restrict__ xg_old, const __half* __restrict__ xc_old,
    const float* __restrict__ dinv,
    const float* __restrict__ W_gcn, const float* __restrict__ b_gcn,
    const float* __restrict__ eps_cg, const float* __restrict__ W_cg,
    const float* __restrict__ b_cg,
    const float* __restrict__ ls, const float* __restrict__ lb,
    __half* __restrict__ xg_new, int n) {
  int i = (int)(((size_t)blockIdx.x * blockDim.x + threadIdx.x) >> 6);
  int lane = threadIdx.x & 63;
  if (i >= n) return;
  int iu = __builtin_amdgcn_readfirstlane(i);
  int ge0 = __builtin_amdgcn_readfirstlane(rp_gg[iu]);
  int ge1 = __builtin_amdgcn_readfirstlane(rp_gg[iu + 1]);
  int fe0 = __builtin_amdgcn_readfirstlane(rp_cg[iu]);
  int fe1 = __builtin_amdgcn_readfirstlane(rp_cg[iu + 1]);
  float self = __half2float(xg_old[(size_t)iu * D + lane]);
  float di = dinv[iu];
  float accG = di * di * self
             + csr_gather_s2(srcbuf, nrm_gg, xg_old, ge0, ge1, lane);
  float accC = csr_gather_s2(srcbuf, nullptr, xc_old, fe0, fe1, lane);
  float gcn = b_gcn[lane];
#pragma unroll
  for (int k = 0; k < 64; ++k)
    gcn = fmaf(bcast_lane(accG, k), W_gcn[k * 64 + lane], gcn);
  float h = (1.0f + eps_cg[0]) * self + accC;
  float gin = b_cg[lane];
#pragma unroll
  for (int k = 0; k < 64; ++k)
    gin = fmaf(bcast_lane(h, k), W_cg[k * 64 + lane], gin);
  float g = gcn + fmaxf(gin, 0.0f);
  float m = wave_sum64(g) * (1.0f / 64.0f);
  float d = g - m;
  float var = wave_sum64(d * d) * (1.0f / 64.0f);
  float o = d * rsqrtf(var + LN_EPS) * ls[lane] + lb[lane];
  xg_new[(size_t)iu * D + lane] = __float2half(fmaxf(o, 0.0f));
}

// ---------------- fused cell layer ------------------------------------------
__global__ __launch_bounds__(256) void cell_layer_kernel(
    const int* __restrict__ rp_cc, const int* __restrict__ srcbuf,
    const __half* __restrict__ xc_old,
    const float* __restrict__ eps_cc, const float* __restrict__ W_cc,
    const float* __restrict__ b_cc,
    const float* __restrict__ ls, const float* __restrict__ lb,
    __half* __restrict__ xc_new, int n) {
  int i = (int)(((size_t)blockIdx.x * blockDim.x + threadIdx.x) >> 6);
  int lane = threadIdx.x & 63;
  if (i >= n) return;
  int iu = __builtin_amdgcn_readfirstlane(i);
  int e0 = __builtin_amdgcn_readfirstlane(rp_cc[iu]);
  int e1 = __builtin_amdgcn_readfirstlane(rp_cc[iu + 1]);
  float self = __half2float(xc_old[(size_t)iu * D + lane]);
  float acc = csr_gather_s2(srcbuf, nullptr, xc_old, e0, e1, lane);
  float h = (1.0f + eps_cc[0]) * self + acc;
  float gin = b_cc[lane];
#pragma unroll
  for (int k = 0; k < 64; ++k)
    gin = fmaf(bcast_lane(h, k), W_cc[k * 64 + lane], gin);
  float g = fmaxf(gin, 0.0f);
  float m = wave_sum64(g) * (1.0f / 64.0f);
  float d = g - m;
  float var = wave_sum64(d * d) * (1.0f / 64.0f);
  float o = d * rsqrtf(var + LN_EPS) * ls[lane] + lb[lane];
  xc_new[(size_t)iu * D + lane] = __float2half(fmaxf(o, 0.0f));
}

// ---------------- output head: wave per row --------------------------------
__global__ __launch_bounds__(256) void out_kernel(
    const __half* __restrict__ xg, const float* __restrict__ W,
    const float* __restrict__ b, float* __restrict__ out, int n) {
  int wid = (int)(((size_t)blockIdx.x * blockDim.x + threadIdx.x) >> 6);
  int lane = threadIdx.x & 63;
  if (wid >= n) return;
  float v = __half2float(xg[(size_t)wid * D + lane]);
  float a0 = wave_sum64(v * W[lane * 3 + 0]) + b[0];
  float a1 = wave_sum64(v * W[lane * 3 + 1]) + b[1];
  float a2 = wave_sum64(v * W[lane * 3 + 2]) + b[2];
  float m = fmaxf(a0, fmaxf(a1, a2));
  float e0 = expf(a0 - m), e1 = expf(a1 - m), e2 = expf(a2 - m);
  float inv = 1.0f / (e0 + e1 + e2);
  if (lane == 0) {
    out[(size_t)wid * 3 + 0] = e0 * inv;
    out[(size_t)wid * 3 + 1] = e1 * inv;
    out[(size_t)wid * 3 + 2] = e2 * inv;
  }
}

extern "C" void kernel_launch(void* const* d_in, const int* in_sizes, int n_in,
                              void* d_out, int out_size, void* d_ws, size_t ws_size,
                              hipStream_t stream) {
  const float* x_glom = (const float*)d_in[0];
  const float* x_cell = (const float*)d_in[1];
  const int*   ei_gg  = (const int*)d_in[2];
  const float* ew_gg  = (const float*)d_in[3];
  const int*   ei_cg  = (const int*)d_in[4];
  const int*   ei_cc  = (const int*)d_in[5];
  const float* W_in_g = (const float*)d_in[6];
  const float* b_in_g = (const float*)d_in[7];
  const float* lnig_s = (const float*)d_in[8];
  const float* lnig_b = (const float*)d_in[9];
  const float* W_in_c = (const float*)d_in[10];
  const float* b_in_c = (const float*)d_in[11];
  const float* lnic_s = (const float*)d_in[12];
  const float* lnic_b = (const float*)d_in[13];
  const float* W_outp = (const float*)d_in[34];
  const float* b_outp = (const float*)d_in[35];

  // ---- workspace layout ----
  char* P = (char*)d_ws;
  __half* xg0 = (__half*)P;                    P += (size_t)NG * D * 2;
  __half* xg1 = (__half*)P;                    P += (size_t)NG * D * 2;
  __half* xc0 = (__half*)P;                    P += (size_t)NC * D * 2;
  __half* xc1 = (__half*)P;                    P += (size_t)NC * D * 2;
  float* dinv = (float*)P;                     P += (size_t)NG * 4;
  float* nrm  = (float*)P;                     P += (size_t)EGG * 4;
  int* S      = (int*)P;                       P += (size_t)(SCAN_N + 1) * 4;
  int* srcbuf = (int*)P;                       P += (size_t)E_ALL * 4;
  int* bhist  = (int*)P;                       P += (size_t)NBKT * NBLK * 4;
  int* base   = (int*)P;                       P += (size_t)NBKT * NBLK * 4;
  int* btot   = (int*)P;                       P += (size_t)NBKT * 4;
  int* bbase  = (int*)P;                       P += (size_t)(NBKT + 1) * 4;
  // transients over the feature-table region (dead before fc_in writes it)
  int* ssort   = (int*)d_ws;
  float* wsort = (float*)(ssort + E_ALL);
  float* ewp   = wsort + EGG;

  dim3 blk(256);
  auto wgrid = [](long long waves) { return dim3((unsigned)((waves + 3) / 4)); };

  // ---- CSR build: atomic-free two-level counting sort ----
  hipMemsetAsync(btot, 0, NBKT * sizeof(int), stream);
  r1_hist_kernel<<<dim3(NBLK), blk, 0, stream>>>(ei_gg, ei_cg, ei_cc, bhist, btot);
  r2b_kernel<<<dim3(1), dim3(256), 0, stream>>>(btot, bbase, S);
  r2c_kernel<<<dim3(NBKT), dim3(512), 0, stream>>>(bhist, bbase, base);
  r3_scatter_kernel<<<dim3(NBLK), blk, 0, stream>>>(
      ei_gg, ew_gg, ei_cg, ei_cc, base, ssort, wsort);
  r4_sort_kernel<<<dim3(NBKT), dim3(1024), 0, stream>>>(
      ssort, wsort, bbase, S, srcbuf, ewp);
  deg_kernel<<<wgrid(NG), blk, 0, stream>>>(S, ewp, dinv);
  nrm_kernel<<<wgrid(NG), blk, 0, stream>>>(S, srcbuf, ewp, dinv, nrm);

  // ---- input FCs via MFMA (overwrite the transient ssort/wsort/ewp region) --
  fc_in_mfma_kernel<<<wgrid(NG / 16), blk, 0, stream>>>(
      x_glom, W_in_g, b_in_g, lnig_s, lnig_b, xg0, NG);
  fc_in_mfma_kernel<<<wgrid(NC / 16), blk, 0, stream>>>(
      x_cell, W_in_c, b_in_c, lnic_s, lnic_b, xc0, NC);

  // ---- two hetero MP layers (split kernels, double-buffered) ----
  const int* rp_gg = S;
  const int* rp_cg = S + NG;
  const int* rp_cc = S + 2 * NG;
  __half* xg_cur = xg0; __half* xg_nxt = xg1;
  __half* xc_cur = xc0; __half* xc_nxt = xc1;
  for (int l = 0; l < 2; ++l) {
    const float* const* p = (const float* const*)(d_in + 14 + 10 * l);
    const float* W_gcn = p[0]; const float* b_gcn = p[1];
    const float* eps_cg = p[2]; const float* W_cg = p[3]; const float* b_cg = p[4];
    const float* eps_cc = p[5]; const float* W_cc = p[6]; const float* b_cc = p[7];
    const float* ln_s = p[8]; const float* ln_b = p[9];

    glom_layer_kernel<<<wgrid(NG), blk, 0, stream>>>(
        rp_gg, rp_cg, srcbuf, nrm, xg_cur, xc_cur, dinv,
        W_gcn, b_gcn, eps_cg, W_cg, b_cg, ln_s, ln_b, xg_nxt, NG);
    cell_layer_kernel<<<wgrid(NC), blk, 0, stream>>>(
        rp_cc, srcbuf, xc_cur, eps_cc, W_cc, b_cc, ln_s, ln_b, xc_nxt, NC);

    __half* t;
    t = xg_cur; xg_cur = xg_nxt; xg_nxt = t;
    t = xc_cur; xc_cur = xc_nxt; xc_nxt = t;
  }

  out_kernel<<<wgrid(NG), blk, 0, stream>>>(xg_cur, W_outp, b_outp, (float*)d_out, NG);
}